// Round 13
// baseline (684.522 us; speedup 1.0000x reference)
//
#include <hip/hip_runtime.h>
#include <math.h>

#define TT 64
#define FF 32
#define HH 64
#define NN 16     // nodes per block
#define GG1 64
#define GG2 32

typedef float f32x4 __attribute__((ext_vector_type(4)));
typedef short bf16x8 __attribute__((ext_vector_type(8)));

__device__ __forceinline__ float fexp2(float x){ return __builtin_amdgcn_exp2f(x); }
__device__ __forceinline__ float frcp (float x){ return __builtin_amdgcn_rcpf(x); }
#define L2E 1.442695041f
__device__ __forceinline__ float sigm_nb(float v, float nb){
  return frcp(1.0f + fexp2(fmaf(v, -L2E, nb)));
}
__device__ __forceinline__ float tanh_b(float v, float b2){
  return fmaf(-2.0f, frcp(1.0f + fexp2(fmaf(v, 2.0f*L2E, b2))), 1.0f);
}
__device__ __forceinline__ float tanh0(float v){
  return fmaf(-2.0f, frcp(1.0f + fexp2(2.0f*L2E*v)), 1.0f);
}

// lane <-> lane^8 exchange within rows of 16 lanes (DPP row_ror:8, VALU pipe)
__device__ __forceinline__ float xor8(float v){
  int a = __builtin_bit_cast(int, v);
  int b = __builtin_amdgcn_update_dpp(0, a, 0x128, 0xF, 0xF, true);
  return __builtin_bit_cast(float, b);
}

__device__ __forceinline__ unsigned short bf16rn(float x){
  unsigned u = __builtin_bit_cast(unsigned, x);
  return (unsigned short)((u + 0x7FFFu + ((u >> 16) & 1u)) >> 16);
}
__device__ __forceinline__ void split2(float x, unsigned short& h, unsigned short& l){
  unsigned u = __builtin_bit_cast(unsigned, x);
  unsigned hr = (u + 0x7FFFu + ((u >> 16) & 1u)) & 0xFFFF0000u;
  h = (unsigned short)(hr >> 16);
  l = bf16rn(x - __builtin_bit_cast(float, hr));
}
// packed split of 2 values via v_cvt_pk_bf16_f32 (HW RNE)
__device__ __forceinline__ void split_pk(float a, float b, unsigned& hi2, unsigned& lo2){
  asm("v_cvt_pk_bf16_f32 %0, %1, %2" : "=v"(hi2) : "v"(a), "v"(b));
  float ha = __builtin_bit_cast(float, hi2 << 16);
  float hb = __builtin_bit_cast(float, hi2 & 0xFFFF0000u);
  float la = a - ha, lb = b - hb;
  asm("v_cvt_pk_bf16_f32 %0, %1, %2" : "=v"(lo2) : "v"(la), "v"(lb));
}

#define PIN(v) asm volatile("" : "+v"(v))
#define MFMA(acc, a, b) (acc) = __builtin_amdgcn_mfma_f32_16x16x32_bf16((a), (b), (acc), 0, 0, 0)

__device__ __forceinline__ void wsplit(const float* p, bf16x8& hi, bf16x8& lo){
  float4 a = *(const float4*)p;
  float4 b = *(const float4*)(p + 4);
  unsigned short h, s;
  split2(a.x,h,s); hi[0]=(short)h; lo[0]=(short)s;
  split2(a.y,h,s); hi[1]=(short)h; lo[1]=(short)s;
  split2(a.z,h,s); hi[2]=(short)h; lo[2]=(short)s;
  split2(a.w,h,s); hi[3]=(short)h; lo[3]=(short)s;
  split2(b.x,h,s); hi[4]=(short)h; lo[4]=(short)s;
  split2(b.y,h,s); hi[5]=(short)h; lo[5]=(short)s;
  split2(b.z,h,s); hi[6]=(short)h; lo[6]=(short)s;
  split2(b.w,h,s); hi[7]=(short)h; lo[7]=(short)s;
}

// ---------------------------------------------------------------------------
// Fused 2-layer LSTM on MFMA, bf16 hi/lo emulated-fp32 (3-pass), in-register
// DPP combine. ROUND-13: role-split 16-wave block (4 waves/SIMD) with a
// DEPHASED 2-phase schedule so the matrix and VALU pipes overlap by
// construction:
//   Phase 1: L0 waves MFMA G0(t)          || L1 waves combine C1(t-2) (VALU)
//   Phase 2: L0 waves combine C0(t) (VALU)|| L1 waves MFMA G1(t-1)
// No work duplication; h1 needs only a single time-buffer (write P1, read P2,
// overwritten next P1 after last read). 2 barriers/t.
// ---------------------------------------------------------------------------
__global__ __launch_bounds__(1024, 4)
void lstm_mfma(const float* __restrict__ x,
    const float* __restrict__ Wih0, const float* __restrict__ Whh0,
    const float* __restrict__ bih0, const float* __restrict__ bhh0,
    const float* __restrict__ Wih1, const float* __restrict__ Whh1,
    const float* __restrict__ bih1, const float* __restrict__ bhh1,
    float* __restrict__ hout, int n)
{
  const int tid  = threadIdx.x;
  const int wv   = tid >> 6;     // wave 0..15
  const int role = wv >> 3;      // 0 = layer0 waves, 1 = layer1 waves
  const int w    = wv & 7;       // col-group within role
  const int l    = tid & 63;
  const int lr   = l & 15;       // A row (node) / B,D col-slot
  const int lg   = l >> 4;       // k-group 0..3
  const int nA   = blockIdx.x * NN;
  int avail = n - nA; if (avail > NN) avail = NN;

  __shared__ short Ax[2][2][16][40];   // [buf][hi/lo][node][f]
  __shared__ short H0[2][2][16][88];   // [buf][hi/lo][node][m]
  __shared__ short H1[2][16][88];      // [hi/lo][node][m] single time-buffer

  const int jm   = lr & 7;
  const bool lo8 = (lr < 8);
  const int col0 = lo8 ? (8*w + jm) : (64  + 8*w + jm);       // i | f
  const int col1 = lo8 ? (128 + 8*w + jm) : (192 + 8*w + jm); // g | o

  // ---- role-dependent weights -> split register fragments ----
  // role 0: [0]=x k0-31, [1]=h0 k0-31, [2]=h0 k32-63
  // role 1: [0]=h0 k0-31, [1]=h0 k32-63, [2]=h1 k0-31, [3]=h1 k32-63
  bf16x8 Wh[2][4], Wl[2][4];
  if (role == 0){
#pragma unroll
    for (int h = 0; h < 2; ++h){
      const int col = h ? col1 : col0;
      wsplit(Wih0 + col*FF + 8*lg,      Wh[h][0], Wl[h][0]);
      wsplit(Whh0 + col*HH + 8*lg,      Wh[h][1], Wl[h][1]);
      wsplit(Whh0 + col*HH + 32 + 8*lg, Wh[h][2], Wl[h][2]);
      Wh[h][3] = Wh[h][2]; Wl[h][3] = Wl[h][2];
    }
  } else {
#pragma unroll
    for (int h = 0; h < 2; ++h){
      const int col = h ? col1 : col0;
      wsplit(Wih1 + col*HH + 8*lg,      Wh[h][0], Wl[h][0]);
      wsplit(Wih1 + col*HH + 32 + 8*lg, Wh[h][1], Wl[h][1]);
      wsplit(Whh1 + col*HH + 8*lg,      Wh[h][2], Wl[h][2]);
      wsplit(Whh1 + col*HH + 32 + 8*lg, Wh[h][3], Wl[h][3]);
    }
  }
#pragma unroll
  for (int h = 0; h < 2; ++h)
#pragma unroll
    for (int k = 0; k < 4; ++k){ PIN(Wh[h][k]); PIN(Wl[h][k]); }

  // ---- per-lane pre-scaled gate biases for this role's layer, col m ----
  const int m = 8*w + jm;
  const float* bi = role ? bih1 : bih0;
  const float* bh = role ? bhh1 : bhh0;
  const float nb_i = -L2E      * (bi[m      ] + bh[m      ]);
  const float nb_f = -L2E      * (bi[m +  64] + bh[m +  64]);
  const float b2_g =  2.0f*L2E * (bi[m + 128] + bh[m + 128]);
  const float nb_o = -L2E      * (bi[m + 192] + bh[m + 192]);

  // ---- zero h planes; stage x(0) ----
  {
    short* p0 = &H0[0][0][0][0];
    for (int i = tid; i < 2*2*16*88; i += 1024) p0[i] = 0;
    short* p1 = &H1[0][0][0];
    for (int i = tid; i < 2*16*88; i += 1024) p1[i] = 0;
    if (tid < 512){
      const int xnd = tid >> 5, xf = tid & 31;
      float v = (xnd < avail) ? x[((size_t)(nA+xnd)*TT + 0)*FF + xf] : 0.0f;
      unsigned short hh, hl; split2(v, hh, hl);
      Ax[0][0][xnd][xf] = (short)hh;
      Ax[0][1][xnd][xf] = (short)hl;
    }
  }
  const int na = 4*lg + (lo8 ? 0 : 2);
  const int nb = na + 1;
  float ca = 0.0f, cb = 0.0f;    // this role's 2 cells at (na,m),(nb,m)
  f32x4 D0 = {0.f,0.f,0.f,0.f}, D1 = {0.f,0.f,0.f,0.f};  // L1 gate accs (cross-iter)
  const f32x4 Z = {0.f, 0.f, 0.f, 0.f};
  __syncthreads();

  for (int t = 0; t < TT; ++t){
    const int rd0 = (t & 1) ^ 1;   // h0(t-1)
    const int wr0 =  t & 1;        // h0(t)
    f32x4 A0, A1;                  // L0 gate accs (phase1 -> phase2)
    float xv = 0.0f;

    // ================== PHASE 1: L0 MFMA || L1 combine ==================
    if (role == 0){
      const int xnd = tid >> 5, xf = tid & 31;
      const int tp = t + 1;
      if (tp < TT && xnd < avail) xv = x[((size_t)(nA+xnd)*TT + tp)*FF + xf];

      bf16x8 axh  = *(const bf16x8*)&Ax[t&1][0][lr][8*lg];
      bf16x8 axl  = *(const bf16x8*)&Ax[t&1][1][lr][8*lg];
      bf16x8 h0ah = *(const bf16x8*)&H0[rd0][0][lr][8*lg];
      bf16x8 h0al = *(const bf16x8*)&H0[rd0][1][lr][8*lg];
      bf16x8 h0bh = *(const bf16x8*)&H0[rd0][0][lr][32+8*lg];
      bf16x8 h0bl = *(const bf16x8*)&H0[rd0][1][lr][32+8*lg];

      __builtin_amdgcn_s_setprio(1);
      A0 = __builtin_amdgcn_mfma_f32_16x16x32_bf16(axl, Wh[0][0], Z, 0, 0, 0);
      A1 = __builtin_amdgcn_mfma_f32_16x16x32_bf16(axl, Wh[1][0], Z, 0, 0, 0);
      MFMA(A0, axh,  Wl[0][0]); MFMA(A0, axh,  Wh[0][0]);
      MFMA(A1, axh,  Wl[1][0]); MFMA(A1, axh,  Wh[1][0]);
      MFMA(A0, h0al, Wh[0][1]); MFMA(A0, h0ah, Wl[0][1]); MFMA(A0, h0ah, Wh[0][1]);
      MFMA(A1, h0al, Wh[1][1]); MFMA(A1, h0ah, Wl[1][1]); MFMA(A1, h0ah, Wh[1][1]);
      MFMA(A0, h0bl, Wh[0][2]); MFMA(A0, h0bh, Wl[0][2]); MFMA(A0, h0bh, Wh[0][2]);
      MFMA(A1, h0bl, Wh[1][2]); MFMA(A1, h0bh, Wl[1][2]); MFMA(A1, h0bh, Wh[1][2]);
      __builtin_amdgcn_s_setprio(0);
    }
    else if (t >= 2){
      // combine C1(t-2) from D0,D1 -> h1(t-2)
      f32x4 s0, s1;
      s0[0]=xor8(D0[0]); s0[1]=xor8(D0[1]); s0[2]=xor8(D0[2]); s0[3]=xor8(D0[3]);
      s1[0]=xor8(D1[0]); s1[1]=xor8(D1[1]); s1[2]=xor8(D1[2]); s1[3]=xor8(D1[3]);
      float gi_a = lo8 ? D0[0] : s0[2],  gi_b = lo8 ? D0[1] : s0[3];
      float gf_a = lo8 ? s0[0] : D0[2],  gf_b = lo8 ? s0[1] : D0[3];
      float gg_a = lo8 ? D1[0] : s1[2],  gg_b = lo8 ? D1[1] : s1[3];
      float go_a = lo8 ? s1[0] : D1[2],  go_b = lo8 ? s1[1] : D1[3];
      ca = sigm_nb(gf_a, nb_f)*ca + sigm_nb(gi_a, nb_i)*tanh_b(gg_a, b2_g);
      float ha = sigm_nb(go_a, nb_o)*tanh0(ca);
      cb = sigm_nb(gf_b, nb_f)*cb + sigm_nb(gi_b, nb_i)*tanh_b(gg_b, b2_g);
      float hb = sigm_nb(go_b, nb_o)*tanh0(cb);
      unsigned hi2, lo2; split_pk(ha, hb, hi2, lo2);
      H1[0][na][m] = (short)(hi2 & 0xFFFF);
      H1[0][nb][m] = (short)(hi2 >> 16);
      H1[1][na][m] = (short)(lo2 & 0xFFFF);
      H1[1][nb][m] = (short)(lo2 >> 16);
    }
    __syncthreads();

    // ================== PHASE 2: L0 combine || L1 MFMA ==================
    if (role == 0){
      // combine C0(t) from A0,A1 -> h0(t)
      f32x4 s0, s1;
      s0[0]=xor8(A0[0]); s0[1]=xor8(A0[1]); s0[2]=xor8(A0[2]); s0[3]=xor8(A0[3]);
      s1[0]=xor8(A1[0]); s1[1]=xor8(A1[1]); s1[2]=xor8(A1[2]); s1[3]=xor8(A1[3]);
      float gi_a = lo8 ? A0[0] : s0[2],  gi_b = lo8 ? A0[1] : s0[3];
      float gf_a = lo8 ? s0[0] : A0[2],  gf_b = lo8 ? s0[1] : A0[3];
      float gg_a = lo8 ? A1[0] : s1[2],  gg_b = lo8 ? A1[1] : s1[3];
      float go_a = lo8 ? s1[0] : A1[2],  go_b = lo8 ? s1[1] : A1[3];
      ca = sigm_nb(gf_a, nb_f)*ca + sigm_nb(gi_a, nb_i)*tanh_b(gg_a, b2_g);
      float ha = sigm_nb(go_a, nb_o)*tanh0(ca);
      cb = sigm_nb(gf_b, nb_f)*cb + sigm_nb(gi_b, nb_i)*tanh_b(gg_b, b2_g);
      float hb = sigm_nb(go_b, nb_o)*tanh0(cb);
      unsigned hi2, lo2; split_pk(ha, hb, hi2, lo2);
      H0[wr0][0][na][m] = (short)(hi2 & 0xFFFF);
      H0[wr0][0][nb][m] = (short)(hi2 >> 16);
      H0[wr0][1][na][m] = (short)(lo2 & 0xFFFF);
      H0[wr0][1][nb][m] = (short)(lo2 >> 16);
      // stage x(t+1)
      const int xnd = tid >> 5, xf = tid & 31;
      const int tp = t + 1;
      if (tp < TT){
        unsigned short hh, hl; split2(xv, hh, hl);
        Ax[tp&1][0][xnd][xf] = (short)hh;
        Ax[tp&1][1][xnd][xf] = (short)hl;
      }
    }
    else if (t >= 1){
      // MFMA G1(t-1): reads h0(t-1) and h1(t-2)
      bf16x8 h0ah = *(const bf16x8*)&H0[rd0][0][lr][8*lg];
      bf16x8 h0al = *(const bf16x8*)&H0[rd0][1][lr][8*lg];
      bf16x8 h0bh = *(const bf16x8*)&H0[rd0][0][lr][32+8*lg];
      bf16x8 h0bl = *(const bf16x8*)&H0[rd0][1][lr][32+8*lg];

      __builtin_amdgcn_s_setprio(1);
      D0 = __builtin_amdgcn_mfma_f32_16x16x32_bf16(h0al, Wh[0][0], Z, 0, 0, 0);
      D1 = __builtin_amdgcn_mfma_f32_16x16x32_bf16(h0al, Wh[1][0], Z, 0, 0, 0);
      MFMA(D0, h0ah, Wl[0][0]); MFMA(D0, h0ah, Wh[0][0]);
      MFMA(D1, h0ah, Wl[1][0]); MFMA(D1, h0ah, Wh[1][0]);
      MFMA(D0, h0bl, Wh[0][1]); MFMA(D0, h0bh, Wl[0][1]); MFMA(D0, h0bh, Wh[0][1]);
      MFMA(D1, h0bl, Wh[1][1]); MFMA(D1, h0bh, Wl[1][1]); MFMA(D1, h0bh, Wh[1][1]);
      bf16x8 h1ah = *(const bf16x8*)&H1[0][lr][8*lg];
      bf16x8 h1al = *(const bf16x8*)&H1[1][lr][8*lg];
      bf16x8 h1bh = *(const bf16x8*)&H1[0][lr][32+8*lg];
      bf16x8 h1bl = *(const bf16x8*)&H1[1][lr][32+8*lg];
      MFMA(D0, h1al, Wh[0][2]); MFMA(D0, h1ah, Wl[0][2]); MFMA(D0, h1ah, Wh[0][2]);
      MFMA(D1, h1al, Wh[1][2]); MFMA(D1, h1ah, Wl[1][2]); MFMA(D1, h1ah, Wh[1][2]);
      MFMA(D0, h1bl, Wh[0][3]); MFMA(D0, h1bh, Wl[0][3]); MFMA(D0, h1bh, Wh[0][3]);
      MFMA(D1, h1bl, Wh[1][3]); MFMA(D1, h1bh, Wl[1][3]); MFMA(D1, h1bh, Wh[1][3]);
      __builtin_amdgcn_s_setprio(0);
    }
    __syncthreads();
  }

  // ================== epilogue ==================
  // D regs hold G1(TT-2). Finish C1(TT-2), then G1(TT-1)+C1(TT-1) -> hout.
  if (role == 1){
    f32x4 s0, s1;
    s0[0]=xor8(D0[0]); s0[1]=xor8(D0[1]); s0[2]=xor8(D0[2]); s0[3]=xor8(D0[3]);
    s1[0]=xor8(D1[0]); s1[1]=xor8(D1[1]); s1[2]=xor8(D1[2]); s1[3]=xor8(D1[3]);
    float gi_a = lo8 ? D0[0] : s0[2],  gi_b = lo8 ? D0[1] : s0[3];
    float gf_a = lo8 ? s0[0] : D0[2],  gf_b = lo8 ? s0[1] : D0[3];
    float gg_a = lo8 ? D1[0] : s1[2],  gg_b = lo8 ? D1[1] : s1[3];
    float go_a = lo8 ? s1[0] : D1[2],  go_b = lo8 ? s1[1] : D1[3];
    ca = sigm_nb(gf_a, nb_f)*ca + sigm_nb(gi_a, nb_i)*tanh_b(gg_a, b2_g);
    float ha = sigm_nb(go_a, nb_o)*tanh0(ca);
    cb = sigm_nb(gf_b, nb_f)*cb + sigm_nb(gi_b, nb_i)*tanh_b(gg_b, b2_g);
    float hb = sigm_nb(go_b, nb_o)*tanh0(cb);
    unsigned hi2, lo2; split_pk(ha, hb, hi2, lo2);
    H1[0][na][m] = (short)(hi2 & 0xFFFF);
    H1[0][nb][m] = (short)(hi2 >> 16);
    H1[1][na][m] = (short)(lo2 & 0xFFFF);
    H1[1][nb][m] = (short)(lo2 >> 16);
  }
  __syncthreads();
  if (role == 1){
    const int rd0 = (TT-1) & 1;      // h0(TT-1)
    bf16x8 h0ah = *(const bf16x8*)&H0[rd0][0][lr][8*lg];
    bf16x8 h0al = *(const bf16x8*)&H0[rd0][1][lr][8*lg];
    bf16x8 h0bh = *(const bf16x8*)&H0[rd0][0][lr][32+8*lg];
    bf16x8 h0bl = *(const bf16x8*)&H0[rd0][1][lr][32+8*lg];
    bf16x8 h1ah = *(const bf16x8*)&H1[0][lr][8*lg];
    bf16x8 h1al = *(const bf16x8*)&H1[1][lr][8*lg];
    bf16x8 h1bh = *(const bf16x8*)&H1[0][lr][32+8*lg];
    bf16x8 h1bl = *(const bf16x8*)&H1[1][lr][32+8*lg];
    f32x4 E0 = __builtin_amdgcn_mfma_f32_16x16x32_bf16(h0al, Wh[0][0], Z, 0, 0, 0);
    f32x4 E1 = __builtin_amdgcn_mfma_f32_16x16x32_bf16(h0al, Wh[1][0], Z, 0, 0, 0);
    MFMA(E0, h0ah, Wl[0][0]); MFMA(E0, h0ah, Wh[0][0]);
    MFMA(E1, h0ah, Wl[1][0]); MFMA(E1, h0ah, Wh[1][0]);
    MFMA(E0, h0bl, Wh[0][1]); MFMA(E0, h0bh, Wl[0][1]); MFMA(E0, h0bh, Wh[0][1]);
    MFMA(E1, h0bl, Wh[1][1]); MFMA(E1, h0bh, Wl[1][1]); MFMA(E1, h0bh, Wh[1][1]);
    MFMA(E0, h1al, Wh[0][2]); MFMA(E0, h1ah, Wl[0][2]); MFMA(E0, h1ah, Wh[0][2]);
    MFMA(E1, h1al, Wh[1][2]); MFMA(E1, h1ah, Wl[1][2]); MFMA(E1, h1ah, Wh[1][2]);
    MFMA(E0, h1bl, Wh[0][3]); MFMA(E0, h1bh, Wl[0][3]); MFMA(E0, h1bh, Wh[0][3]);
    MFMA(E1, h1bl, Wh[1][3]); MFMA(E1, h1bh, Wl[1][3]); MFMA(E1, h1bh, Wh[1][3]);

    f32x4 s0, s1;
    s0[0]=xor8(E0[0]); s0[1]=xor8(E0[1]); s0[2]=xor8(E0[2]); s0[3]=xor8(E0[3]);
    s1[0]=xor8(E1[0]); s1[1]=xor8(E1[1]); s1[2]=xor8(E1[2]); s1[3]=xor8(E1[3]);
    float gi_a = lo8 ? E0[0] : s0[2],  gi_b = lo8 ? E0[1] : s0[3];
    float gf_a = lo8 ? s0[0] : E0[2],  gf_b = lo8 ? s0[1] : E0[3];
    float gg_a = lo8 ? E1[0] : s1[2],  gg_b = lo8 ? E1[1] : s1[3];
    float go_a = lo8 ? s1[0] : E1[2],  go_b = lo8 ? s1[1] : E1[3];
    ca = sigm_nb(gf_a, nb_f)*ca + sigm_nb(gi_a, nb_i)*tanh_b(gg_a, b2_g);
    float ha = sigm_nb(go_a, nb_o)*tanh0(ca);
    cb = sigm_nb(gf_b, nb_f)*cb + sigm_nb(gi_b, nb_i)*tanh_b(gg_b, b2_g);
    float hb = sigm_nb(go_b, nb_o)*tanh0(cb);
    if (nA + na < n) hout[(size_t)(nA+na)*HH + m] = ha;
    if (nA + nb < n) hout[(size_t)(nA+nb)*HH + m] = hb;
  }
}

// ---------------------------------------------------------------------------
// GCN support kernels
// ---------------------------------------------------------------------------
__global__ void k_count(const int* __restrict__ dst, int E, int* __restrict__ cnt)
{
  int e = blockIdx.x * blockDim.x + threadIdx.x;
  if (e < E) atomicAdd(&cnt[dst[e]], 1);
}

__global__ void k_scan_build(const int* __restrict__ cnt, int n,
                             int* __restrict__ offs, int* __restrict__ cursor,
                             float* __restrict__ dinv)
{
  __shared__ int part[1024];
  const int tid = threadIdx.x;
  const int per = (n + 1023) >> 10;
  const int base = tid * per;
  int s = 0;
  for (int i = 0; i < per; ++i) { int idx = base + i; if (idx < n) s += cnt[idx]; }
  part[tid] = s;
  __syncthreads();
  for (int off = 1; off < 1024; off <<= 1) {
    int v = 0;
    if (tid >= off) v = part[tid - off];
    __syncthreads();
    part[tid] += v;
    __syncthreads();
  }
  int run = part[tid] - s;
  for (int i = 0; i < per; ++i) {
    int idx = base + i;
    if (idx < n) {
      offs[idx] = run; cursor[idx] = run;
      int c = cnt[idx];
      dinv[idx] = 1.0f / sqrtf((float)(c + 1));
      run += c;
    }
  }
}

__global__ void k_fill(const int* __restrict__ src, const int* __restrict__ dst,
                       int E, int* __restrict__ cursor, int* __restrict__ csr)
{
  int e = blockIdx.x * blockDim.x + threadIdx.x;
  if (e < E) {
    int d = dst[e];
    int pos = atomicAdd(&cursor[d], 1);
    csr[pos] = src[e];
  }
}

template <int K, int M>
__global__ void k_xw(const float* __restrict__ A, const float* __restrict__ W,
                     float* __restrict__ out, int n)
{
  int idx = blockIdx.x * blockDim.x + threadIdx.x;
  int row = idx / M, col = idx % M;
  if (row >= n) return;
  const float* a = A + (size_t)row * K;
  float acc = 0.0f;
#pragma unroll
  for (int k = 0; k < K; ++k) acc = fmaf(a[k], W[k*M + col], acc);
  out[(size_t)row*M + col] = acc;
}

// CSR aggregate for layer1 (FD=64) + bias/relu, FUSED with xw2 = g1 @ W2.
__global__ void k_agg_x2(const float* __restrict__ xw, const int* __restrict__ offs,
                         const int* __restrict__ cnt, const int* __restrict__ csr,
                         const float* __restrict__ dinv, const float* __restrict__ b,
                         const float* __restrict__ W2,
                         float* __restrict__ g1out, float* __restrict__ xw2out, int n)
{
  __shared__ float sg[4][GG1];
  const int nd   = threadIdx.x >> 6;
  const int lane = threadIdx.x & 63;
  const int node = blockIdx.x * 4 + nd;
  if (node < n) {
    const float di = dinv[node];
    float acc = xw[(size_t)node*GG1 + lane] * di * di;
    const int s0 = offs[node], e0 = s0 + cnt[node];
    for (int p = s0; p < e0; ++p) {
      int s = csr[p];
      acc = fmaf(xw[(size_t)s*GG1 + lane], dinv[s] * di, acc);
    }
    float val = fmaxf(acc + b[lane], 0.0f);
    g1out[(size_t)node*GG1 + lane] = val;
    sg[nd][lane] = val;
  }
  __syncthreads();
  if (node < n && lane < GG2) {
    float a2 = 0.0f;
#pragma unroll
    for (int k = 0; k < GG1; ++k) a2 = fmaf(sg[nd][k], W2[k*GG2 + lane], a2);
    xw2out[(size_t)node*GG2 + lane] = a2;
  }
}

template <int FD>
__global__ void k_agg(const float* __restrict__ xw, const int* __restrict__ offs,
                      const int* __restrict__ cnt, const int* __restrict__ csr,
                      const float* __restrict__ dinv, const float* __restrict__ b,
                      float* __restrict__ out, int n)
{
  int gidx = blockIdx.x * blockDim.x + threadIdx.x;
  int node = gidx / FD, lane = gidx % FD;
  if (node >= n) return;
  const float di = dinv[node];
  float acc = xw[(size_t)node*FD + lane] * di * di;
  const int s0 = offs[node], e0 = s0 + cnt[node];
  for (int p = s0; p < e0; ++p) {
    int s = csr[p];
    acc = fmaf(xw[(size_t)s*FD + lane], dinv[s] * di, acc);
  }
  out[(size_t)node*FD + lane] = fmaxf(acc + b[lane], 0.0f);
}

__global__ void k_fc(const float* __restrict__ g2, const int* __restrict__ sid,
                     const float* __restrict__ fcW, const float* __restrict__ fcb,
                     float* __restrict__ out, int n)
{
  int i = blockIdx.x * blockDim.x + threadIdx.x;
  if (i >= n) return;
  const float* row = g2 + (size_t)sid[i] * GG2;
  float acc = fcb[0];
#pragma unroll
  for (int f = 0; f < GG2; ++f) acc = fmaf(row[f], fcW[f], acc);
  out[i] = acc;
}

// ---------------------------------------------------------------------------
extern "C" void kernel_launch(void* const* d_in, const int* in_sizes, int n_in,
                              void* d_out, int out_size, void* d_ws, size_t ws_size,
                              hipStream_t stream)
{
  const float* x    = (const float*)d_in[0];
  const int*   sid  = (const int*)  d_in[1];
  const int*   eidx = (const int*)  d_in[2];
  const float* Wih0 = (const float*)d_in[3];
  const float* Whh0 = (const float*)d_in[4];
  const float* bih0 = (const float*)d_in[5];
  const float* bhh0 = (const float*)d_in[6];
  const float* Wih1 = (const float*)d_in[7];
  const float* Whh1 = (const float*)d_in[8];
  const float* bih1 = (const float*)d_in[9];
  const float* bhh1 = (const float*)d_in[10];
  const float* g1W  = (const float*)d_in[11];
  const float* g1b  = (const float*)d_in[12];
  const float* g2W  = (const float*)d_in[13];
  const float* g2b  = (const float*)d_in[14];
  const float* fcW  = (const float*)d_in[15];
  const float* fcb  = (const float*)d_in[16];

  const int n = in_sizes[1];
  const int E = in_sizes[2] / 2;
  float* out = (float*)d_out;

  char* w = (char*)d_ws;
  auto carve = [&](size_t bytes) -> void* {
    void* p = (void*)w; w += (bytes + 255) & ~(size_t)255; return p;
  };
  float* hfin   = (float*)carve((size_t)n * HH * 4);
  int*   cnt    = (int*)  carve((size_t)n * 4);
  int*   offs   = (int*)  carve((size_t)n * 4);
  int*   cursor = (int*)  carve((size_t)n * 4);
  float* dinv   = (float*)carve((size_t)n * 4);
  int*   csr    = (int*)  carve((size_t)E * 4);
  float* xw1    = (float*)carve((size_t)n * GG1 * 4);
  float* g1     = (float*)carve((size_t)n * GG1 * 4);
  float* xw2    = (float*)carve((size_t)n * GG2 * 4);
  float* g2     = (float*)carve((size_t)n * GG2 * 4);

  const int* src = eidx;
  const int* dst = eidx + E;

  lstm_mfma<<<(n + NN - 1) / NN, 1024, 0, stream>>>(x, Wih0, Whh0, bih0, bhh0,
                                                    Wih1, Whh1, bih1, bhh1, hfin, n);

  hipMemsetAsync(cnt, 0, (size_t)n * 4, stream);
  k_count<<<(E + 255) / 256, 256, 0, stream>>>(dst, E, cnt);
  k_scan_build<<<1, 1024, 0, stream>>>(cnt, n, offs, cursor, dinv);
  k_fill<<<(E + 255) / 256, 256, 0, stream>>>(src, dst, E, cursor, csr);

  k_xw<HH, GG1><<<((size_t)n * GG1 + 255) / 256, 256, 0, stream>>>(hfin, g1W, xw1, n);
  k_agg_x2<<<(n + 3) / 4, 256, 0, stream>>>(xw1, offs, cnt, csr, dinv, g1b, g2W, g1, xw2, n);

  k_agg<GG2><<<((size_t)n * GG2 + 255) / 256, 256, 0, stream>>>(xw2, offs, cnt, csr, dinv, g2b, g2, n);

  k_fc<<<(n + 255) / 256, 256, 0, stream>>>(g2, sid, fcW, fcb, out, n);
}

// Round 15
// 677.518 us; speedup vs baseline: 1.0103x; 1.0103x over previous
//
#include <hip/hip_runtime.h>
#include <math.h>

#define TT 64
#define FF 32
#define HH 64
#define NN 16     // nodes per block
#define GG1 64
#define GG2 32

typedef float f32x4 __attribute__((ext_vector_type(4)));
typedef short bf16x8 __attribute__((ext_vector_type(8)));

__device__ __forceinline__ float fexp2(float x){ return __builtin_amdgcn_exp2f(x); }
__device__ __forceinline__ float frcp (float x){ return __builtin_amdgcn_rcpf(x); }
#define L2E 1.442695041f
__device__ __forceinline__ float sigm_nb(float v, float nb){
  return frcp(1.0f + fexp2(fmaf(v, -L2E, nb)));
}
__device__ __forceinline__ float tanh_b(float v, float b2){
  return fmaf(-2.0f, frcp(1.0f + fexp2(fmaf(v, 2.0f*L2E, b2))), 1.0f);
}
__device__ __forceinline__ float tanh0(float v){
  return fmaf(-2.0f, frcp(1.0f + fexp2(2.0f*L2E*v)), 1.0f);
}

// lane <-> lane^8 exchange within rows of 16 lanes (DPP row_ror:8, VALU pipe)
__device__ __forceinline__ float xor8(float v){
  int a = __builtin_bit_cast(int, v);
  int b = __builtin_amdgcn_update_dpp(0, a, 0x128, 0xF, 0xF, true);
  return __builtin_bit_cast(float, b);
}

__device__ __forceinline__ unsigned short bf16rn(float x){
  unsigned u = __builtin_bit_cast(unsigned, x);
  return (unsigned short)((u + 0x7FFFu + ((u >> 16) & 1u)) >> 16);
}
__device__ __forceinline__ void split2(float x, unsigned short& h, unsigned short& l){
  unsigned u = __builtin_bit_cast(unsigned, x);
  unsigned hr = (u + 0x7FFFu + ((u >> 16) & 1u)) & 0xFFFF0000u;
  h = (unsigned short)(hr >> 16);
  l = bf16rn(x - __builtin_bit_cast(float, hr));
}
// packed split of 2 values via v_cvt_pk_bf16_f32 (HW RNE)
__device__ __forceinline__ void split_pk(float a, float b, unsigned& hi2, unsigned& lo2){
  asm("v_cvt_pk_bf16_f32 %0, %1, %2" : "=v"(hi2) : "v"(a), "v"(b));
  float ha = __builtin_bit_cast(float, hi2 << 16);
  float hb = __builtin_bit_cast(float, hi2 & 0xFFFF0000u);
  float la = a - ha, lb = b - hb;
  asm("v_cvt_pk_bf16_f32 %0, %1, %2" : "=v"(lo2) : "v"(la), "v"(lb));
}

#define PIN(v) asm volatile("" : "+v"(v))
#define MFMA(acc, a, b) (acc) = __builtin_amdgcn_mfma_f32_16x16x32_bf16((a), (b), (acc), 0, 0, 0)

__device__ __forceinline__ void wsplit(const float* p, bf16x8& hi, bf16x8& lo){
  float4 a = *(const float4*)p;
  float4 b = *(const float4*)(p + 4);
  unsigned short h, s;
  split2(a.x,h,s); hi[0]=(short)h; lo[0]=(short)s;
  split2(a.y,h,s); hi[1]=(short)h; lo[1]=(short)s;
  split2(a.z,h,s); hi[2]=(short)h; lo[2]=(short)s;
  split2(a.w,h,s); hi[3]=(short)h; lo[3]=(short)s;
  split2(b.x,h,s); hi[4]=(short)h; lo[4]=(short)s;
  split2(b.y,h,s); hi[5]=(short)h; lo[5]=(short)s;
  split2(b.z,h,s); hi[6]=(short)h; lo[6]=(short)s;
  split2(b.w,h,s); hi[7]=(short)h; lo[7]=(short)s;
}

// ---------------------------------------------------------------------------
// Fused 2-layer LSTM on MFMA, bf16 hi/lo emulated-fp32 (3-pass), in-register
// DPP combine. Round-13 structure (best known): role-split 16-wave block
// (4 waves/SIMD) with dephased 2-phase schedule:
//   Phase 1: L0 waves MFMA G0(t)          || L1 waves combine C1(t-2)
//   Phase 2: L0 waves combine C0(t)       || L1 waves MFMA G1(t-1)
// ROUND-15 delta: epilogue additionally computes xw1 = h1_final @ g1W
// in-block (hf[16][64] fp32 LDS staging; wave==node so hf reads broadcast),
// deleting the separate k_xw kernel and the hfin global round-trip.
// ---------------------------------------------------------------------------
__global__ __launch_bounds__(1024, 4)
void lstm_mfma(const float* __restrict__ x,
    const float* __restrict__ Wih0, const float* __restrict__ Whh0,
    const float* __restrict__ bih0, const float* __restrict__ bhh0,
    const float* __restrict__ Wih1, const float* __restrict__ Whh1,
    const float* __restrict__ bih1, const float* __restrict__ bhh1,
    const float* __restrict__ g1W, float* __restrict__ xw1out, int n)
{
  const int tid  = threadIdx.x;
  const int wv   = tid >> 6;     // wave 0..15
  const int role = wv >> 3;      // 0 = layer0 waves, 1 = layer1 waves
  const int w    = wv & 7;       // col-group within role
  const int l    = tid & 63;
  const int lr   = l & 15;       // A row (node) / B,D col-slot
  const int lg   = l >> 4;       // k-group 0..3
  const int nA   = blockIdx.x * NN;
  int avail = n - nA; if (avail > NN) avail = NN;

  __shared__ short Ax[2][2][16][40];   // [buf][hi/lo][node][f]
  __shared__ short H0[2][2][16][88];   // [buf][hi/lo][node][m]
  __shared__ short H1[2][16][88];      // [hi/lo][node][m] single time-buffer
  __shared__ float hf[16][64];         // final h1 (fp32) for xw1 fusion

  const int jm   = lr & 7;
  const bool lo8 = (lr < 8);
  const int col0 = lo8 ? (8*w + jm) : (64  + 8*w + jm);       // i | f
  const int col1 = lo8 ? (128 + 8*w + jm) : (192 + 8*w + jm); // g | o

  // ---- role-dependent weights -> split register fragments ----
  bf16x8 Wh[2][4], Wl[2][4];
  if (role == 0){
#pragma unroll
    for (int h = 0; h < 2; ++h){
      const int col = h ? col1 : col0;
      wsplit(Wih0 + col*FF + 8*lg,      Wh[h][0], Wl[h][0]);
      wsplit(Whh0 + col*HH + 8*lg,      Wh[h][1], Wl[h][1]);
      wsplit(Whh0 + col*HH + 32 + 8*lg, Wh[h][2], Wl[h][2]);
      Wh[h][3] = Wh[h][2]; Wl[h][3] = Wl[h][2];
    }
  } else {
#pragma unroll
    for (int h = 0; h < 2; ++h){
      const int col = h ? col1 : col0;
      wsplit(Wih1 + col*HH + 8*lg,      Wh[h][0], Wl[h][0]);
      wsplit(Wih1 + col*HH + 32 + 8*lg, Wh[h][1], Wl[h][1]);
      wsplit(Whh1 + col*HH + 8*lg,      Wh[h][2], Wl[h][2]);
      wsplit(Whh1 + col*HH + 32 + 8*lg, Wh[h][3], Wl[h][3]);
    }
  }
#pragma unroll
  for (int h = 0; h < 2; ++h)
#pragma unroll
    for (int k = 0; k < 4; ++k){ PIN(Wh[h][k]); PIN(Wl[h][k]); }

  // ---- per-lane pre-scaled gate biases for this role's layer, col m ----
  const int m = 8*w + jm;
  const float* bi = role ? bih1 : bih0;
  const float* bh = role ? bhh1 : bhh0;
  const float nb_i = -L2E      * (bi[m      ] + bh[m      ]);
  const float nb_f = -L2E      * (bi[m +  64] + bh[m +  64]);
  const float b2_g =  2.0f*L2E * (bi[m + 128] + bh[m + 128]);
  const float nb_o = -L2E      * (bi[m + 192] + bh[m + 192]);

  // ---- zero h planes; stage x(0) ----
  {
    short* p0 = &H0[0][0][0][0];
    for (int i = tid; i < 2*2*16*88; i += 1024) p0[i] = 0;
    short* p1 = &H1[0][0][0];
    for (int i = tid; i < 2*16*88; i += 1024) p1[i] = 0;
    if (tid < 512){
      const int xnd = tid >> 5, xf = tid & 31;
      float v = (xnd < avail) ? x[((size_t)(nA+xnd)*TT + 0)*FF + xf] : 0.0f;
      unsigned short hh, hl; split2(v, hh, hl);
      Ax[0][0][xnd][xf] = (short)hh;
      Ax[0][1][xnd][xf] = (short)hl;
    }
  }
  const int na = 4*lg + (lo8 ? 0 : 2);
  const int nb = na + 1;
  float ca = 0.0f, cb = 0.0f;    // this role's 2 cells at (na,m),(nb,m)
  f32x4 D0 = {0.f,0.f,0.f,0.f}, D1 = {0.f,0.f,0.f,0.f};  // L1 gate accs (cross-iter)
  const f32x4 Z = {0.f, 0.f, 0.f, 0.f};
  __syncthreads();

  for (int t = 0; t < TT; ++t){
    const int rd0 = (t & 1) ^ 1;   // h0(t-1)
    const int wr0 =  t & 1;        // h0(t)
    f32x4 A0, A1;                  // L0 gate accs (phase1 -> phase2)
    float xv = 0.0f;

    // ================== PHASE 1: L0 MFMA || L1 combine ==================
    if (role == 0){
      const int xnd = tid >> 5, xf = tid & 31;
      const int tp = t + 1;
      if (tp < TT && xnd < avail) xv = x[((size_t)(nA+xnd)*TT + tp)*FF + xf];

      bf16x8 axh  = *(const bf16x8*)&Ax[t&1][0][lr][8*lg];
      bf16x8 axl  = *(const bf16x8*)&Ax[t&1][1][lr][8*lg];
      bf16x8 h0ah = *(const bf16x8*)&H0[rd0][0][lr][8*lg];
      bf16x8 h0al = *(const bf16x8*)&H0[rd0][1][lr][8*lg];
      bf16x8 h0bh = *(const bf16x8*)&H0[rd0][0][lr][32+8*lg];
      bf16x8 h0bl = *(const bf16x8*)&H0[rd0][1][lr][32+8*lg];

      __builtin_amdgcn_s_setprio(1);
      A0 = __builtin_amdgcn_mfma_f32_16x16x32_bf16(axl, Wh[0][0], Z, 0, 0, 0);
      A1 = __builtin_amdgcn_mfma_f32_16x16x32_bf16(axl, Wh[1][0], Z, 0, 0, 0);
      MFMA(A0, axh,  Wl[0][0]); MFMA(A0, axh,  Wh[0][0]);
      MFMA(A1, axh,  Wl[1][0]); MFMA(A1, axh,  Wh[1][0]);
      MFMA(A0, h0al, Wh[0][1]); MFMA(A0, h0ah, Wl[0][1]); MFMA(A0, h0ah, Wh[0][1]);
      MFMA(A1, h0al, Wh[1][1]); MFMA(A1, h0ah, Wl[1][1]); MFMA(A1, h0ah, Wh[1][1]);
      MFMA(A0, h0bl, Wh[0][2]); MFMA(A0, h0bh, Wl[0][2]); MFMA(A0, h0bh, Wh[0][2]);
      MFMA(A1, h0bl, Wh[1][2]); MFMA(A1, h0bh, Wl[1][2]); MFMA(A1, h0bh, Wh[1][2]);
      __builtin_amdgcn_s_setprio(0);
    }
    else if (t >= 2){
      // combine C1(t-2) from D0,D1 -> h1(t-2)
      f32x4 s0, s1;
      s0[0]=xor8(D0[0]); s0[1]=xor8(D0[1]); s0[2]=xor8(D0[2]); s0[3]=xor8(D0[3]);
      s1[0]=xor8(D1[0]); s1[1]=xor8(D1[1]); s1[2]=xor8(D1[2]); s1[3]=xor8(D1[3]);
      float gi_a = lo8 ? D0[0] : s0[2],  gi_b = lo8 ? D0[1] : s0[3];
      float gf_a = lo8 ? s0[0] : D0[2],  gf_b = lo8 ? s0[1] : D0[3];
      float gg_a = lo8 ? D1[0] : s1[2],  gg_b = lo8 ? D1[1] : s1[3];
      float go_a = lo8 ? s1[0] : D1[2],  go_b = lo8 ? s1[1] : D1[3];
      ca = sigm_nb(gf_a, nb_f)*ca + sigm_nb(gi_a, nb_i)*tanh_b(gg_a, b2_g);
      float ha = sigm_nb(go_a, nb_o)*tanh0(ca);
      cb = sigm_nb(gf_b, nb_f)*cb + sigm_nb(gi_b, nb_i)*tanh_b(gg_b, b2_g);
      float hb = sigm_nb(go_b, nb_o)*tanh0(cb);
      unsigned hi2, lo2; split_pk(ha, hb, hi2, lo2);
      H1[0][na][m] = (short)(hi2 & 0xFFFF);
      H1[0][nb][m] = (short)(hi2 >> 16);
      H1[1][na][m] = (short)(lo2 & 0xFFFF);
      H1[1][nb][m] = (short)(lo2 >> 16);
    }
    __syncthreads();

    // ================== PHASE 2: L0 combine || L1 MFMA ==================
    if (role == 0){
      f32x4 s0, s1;
      s0[0]=xor8(A0[0]); s0[1]=xor8(A0[1]); s0[2]=xor8(A0[2]); s0[3]=xor8(A0[3]);
      s1[0]=xor8(A1[0]); s1[1]=xor8(A1[1]); s1[2]=xor8(A1[2]); s1[3]=xor8(A1[3]);
      float gi_a = lo8 ? A0[0] : s0[2],  gi_b = lo8 ? A0[1] : s0[3];
      float gf_a = lo8 ? s0[0] : A0[2],  gf_b = lo8 ? s0[1] : A0[3];
      float gg_a = lo8 ? A1[0] : s1[2],  gg_b = lo8 ? A1[1] : s1[3];
      float go_a = lo8 ? s1[0] : A1[2],  go_b = lo8 ? s1[1] : A1[3];
      ca = sigm_nb(gf_a, nb_f)*ca + sigm_nb(gi_a, nb_i)*tanh_b(gg_a, b2_g);
      float ha = sigm_nb(go_a, nb_o)*tanh0(ca);
      cb = sigm_nb(gf_b, nb_f)*cb + sigm_nb(gi_b, nb_i)*tanh_b(gg_b, b2_g);
      float hb = sigm_nb(go_b, nb_o)*tanh0(cb);
      unsigned hi2, lo2; split_pk(ha, hb, hi2, lo2);
      H0[wr0][0][na][m] = (short)(hi2 & 0xFFFF);
      H0[wr0][0][nb][m] = (short)(hi2 >> 16);
      H0[wr0][1][na][m] = (short)(lo2 & 0xFFFF);
      H0[wr0][1][nb][m] = (short)(lo2 >> 16);
      // stage x(t+1)
      const int xnd = tid >> 5, xf = tid & 31;
      const int tp = t + 1;
      if (tp < TT){
        unsigned short hh, hl; split2(xv, hh, hl);
        Ax[tp&1][0][xnd][xf] = (short)hh;
        Ax[tp&1][1][xnd][xf] = (short)hl;
      }
    }
    else if (t >= 1){
      // MFMA G1(t-1): reads h0(t-1) and h1(t-2)
      bf16x8 h0ah = *(const bf16x8*)&H0[rd0][0][lr][8*lg];
      bf16x8 h0al = *(const bf16x8*)&H0[rd0][1][lr][8*lg];
      bf16x8 h0bh = *(const bf16x8*)&H0[rd0][0][lr][32+8*lg];
      bf16x8 h0bl = *(const bf16x8*)&H0[rd0][1][lr][32+8*lg];

      __builtin_amdgcn_s_setprio(1);
      D0 = __builtin_amdgcn_mfma_f32_16x16x32_bf16(h0al, Wh[0][0], Z, 0, 0, 0);
      D1 = __builtin_amdgcn_mfma_f32_16x16x32_bf16(h0al, Wh[1][0], Z, 0, 0, 0);
      MFMA(D0, h0ah, Wl[0][0]); MFMA(D0, h0ah, Wh[0][0]);
      MFMA(D1, h0ah, Wl[1][0]); MFMA(D1, h0ah, Wh[1][0]);
      MFMA(D0, h0bl, Wh[0][1]); MFMA(D0, h0bh, Wl[0][1]); MFMA(D0, h0bh, Wh[0][1]);
      MFMA(D1, h0bl, Wh[1][1]); MFMA(D1, h0bh, Wl[1][1]); MFMA(D1, h0bh, Wh[1][1]);
      bf16x8 h1ah = *(const bf16x8*)&H1[0][lr][8*lg];
      bf16x8 h1al = *(const bf16x8*)&H1[1][lr][8*lg];
      bf16x8 h1bh = *(const bf16x8*)&H1[0][lr][32+8*lg];
      bf16x8 h1bl = *(const bf16x8*)&H1[1][lr][32+8*lg];
      MFMA(D0, h1al, Wh[0][2]); MFMA(D0, h1ah, Wl[0][2]); MFMA(D0, h1ah, Wh[0][2]);
      MFMA(D1, h1al, Wh[1][2]); MFMA(D1, h1ah, Wl[1][2]); MFMA(D1, h1ah, Wh[1][2]);
      MFMA(D0, h1bl, Wh[0][3]); MFMA(D0, h1bh, Wl[0][3]); MFMA(D0, h1bh, Wh[0][3]);
      MFMA(D1, h1bl, Wh[1][3]); MFMA(D1, h1bh, Wl[1][3]); MFMA(D1, h1bh, Wh[1][3]);
      __builtin_amdgcn_s_setprio(0);
    }
    __syncthreads();
  }

  // ================== epilogue ==================
  // D regs hold G1(TT-2). Finish C1(TT-2), then G1(TT-1)+C1(TT-1) -> hf.
  if (role == 1){
    f32x4 s0, s1;
    s0[0]=xor8(D0[0]); s0[1]=xor8(D0[1]); s0[2]=xor8(D0[2]); s0[3]=xor8(D0[3]);
    s1[0]=xor8(D1[0]); s1[1]=xor8(D1[1]); s1[2]=xor8(D1[2]); s1[3]=xor8(D1[3]);
    float gi_a = lo8 ? D0[0] : s0[2],  gi_b = lo8 ? D0[1] : s0[3];
    float gf_a = lo8 ? s0[0] : D0[2],  gf_b = lo8 ? s0[1] : D0[3];
    float gg_a = lo8 ? D1[0] : s1[2],  gg_b = lo8 ? D1[1] : s1[3];
    float go_a = lo8 ? s1[0] : D1[2],  go_b = lo8 ? s1[1] : D1[3];
    ca = sigm_nb(gf_a, nb_f)*ca + sigm_nb(gi_a, nb_i)*tanh_b(gg_a, b2_g);
    float ha = sigm_nb(go_a, nb_o)*tanh0(ca);
    cb = sigm_nb(gf_b, nb_f)*cb + sigm_nb(gi_b, nb_i)*tanh_b(gg_b, b2_g);
    float hb = sigm_nb(go_b, nb_o)*tanh0(cb);
    unsigned hi2, lo2; split_pk(ha, hb, hi2, lo2);
    H1[0][na][m] = (short)(hi2 & 0xFFFF);
    H1[0][nb][m] = (short)(hi2 >> 16);
    H1[1][na][m] = (short)(lo2 & 0xFFFF);
    H1[1][nb][m] = (short)(lo2 >> 16);
  }
  __syncthreads();
  if (role == 1){
    const int rd0 = (TT-1) & 1;      // h0(TT-1)
    bf16x8 h0ah = *(const bf16x8*)&H0[rd0][0][lr][8*lg];
    bf16x8 h0al = *(const bf16x8*)&H0[rd0][1][lr][8*lg];
    bf16x8 h0bh = *(const bf16x8*)&H0[rd0][0][lr][32+8*lg];
    bf16x8 h0bl = *(const bf16x8*)&H0[rd0][1][lr][32+8*lg];
    bf16x8 h1ah = *(const bf16x8*)&H1[0][lr][8*lg];
    bf16x8 h1al = *(const bf16x8*)&H1[1][lr][8*lg];
    bf16x8 h1bh = *(const bf16x8*)&H1[0][lr][32+8*lg];
    bf16x8 h1bl = *(const bf16x8*)&H1[1][lr][32+8*lg];
    f32x4 E0 = __builtin_amdgcn_mfma_f32_16x16x32_bf16(h0al, Wh[0][0], Z, 0, 0, 0);
    f32x4 E1 = __builtin_amdgcn_mfma_f32_16x16x32_bf16(h0al, Wh[1][0], Z, 0, 0, 0);
    MFMA(E0, h0ah, Wl[0][0]); MFMA(E0, h0ah, Wh[0][0]);
    MFMA(E1, h0ah, Wl[1][0]); MFMA(E1, h0ah, Wh[1][0]);
    MFMA(E0, h0bl, Wh[0][1]); MFMA(E0, h0bh, Wl[0][1]); MFMA(E0, h0bh, Wh[0][1]);
    MFMA(E1, h0bl, Wh[1][1]); MFMA(E1, h0bh, Wl[1][1]); MFMA(E1, h0bh, Wh[1][1]);
    MFMA(E0, h1al, Wh[0][2]); MFMA(E0, h1ah, Wl[0][2]); MFMA(E0, h1ah, Wh[0][2]);
    MFMA(E1, h1al, Wh[1][2]); MFMA(E1, h1ah, Wl[1][2]); MFMA(E1, h1ah, Wh[1][2]);
    MFMA(E0, h1bl, Wh[0][3]); MFMA(E0, h1bh, Wl[0][3]); MFMA(E0, h1bh, Wh[0][3]);
    MFMA(E1, h1bl, Wh[1][3]); MFMA(E1, h1bh, Wl[1][3]); MFMA(E1, h1bh, Wh[1][3]);

    f32x4 s0, s1;
    s0[0]=xor8(E0[0]); s0[1]=xor8(E0[1]); s0[2]=xor8(E0[2]); s0[3]=xor8(E0[3]);
    s1[0]=xor8(E1[0]); s1[1]=xor8(E1[1]); s1[2]=xor8(E1[2]); s1[3]=xor8(E1[3]);
    float gi_a = lo8 ? E0[0] : s0[2],  gi_b = lo8 ? E0[1] : s0[3];
    float gf_a = lo8 ? s0[0] : E0[2],  gf_b = lo8 ? s0[1] : E0[3];
    float gg_a = lo8 ? E1[0] : s1[2],  gg_b = lo8 ? E1[1] : s1[3];
    float go_a = lo8 ? s1[0] : E1[2],  go_b = lo8 ? s1[1] : E1[3];
    ca = sigm_nb(gf_a, nb_f)*ca + sigm_nb(gi_a, nb_i)*tanh_b(gg_a, b2_g);
    float ha = sigm_nb(go_a, nb_o)*tanh0(ca);
    cb = sigm_nb(gf_b, nb_f)*cb + sigm_nb(gi_b, nb_i)*tanh_b(gg_b, b2_g);
    float hb = sigm_nb(go_b, nb_o)*tanh0(cb);
    hf[na][m] = ha;
    hf[nb][m] = hb;
  }
  __syncthreads();

  // ---- fused xw1 = h1_final @ g1W (one output per thread; wave==node) ----
  {
    const int node = tid >> 6;     // 0..15  (== wave id, hf reads broadcast)
    const int col  = tid & 63;
    if (node < avail){
      float acc = 0.0f;
#pragma unroll
      for (int k = 0; k < HH; ++k)
        acc = fmaf(hf[node][k], g1W[k*GG1 + col], acc);
      xw1out[(size_t)(nA + node)*GG1 + col] = acc;
    }
  }
}

// ---------------------------------------------------------------------------
// GCN support kernels
// ---------------------------------------------------------------------------
__global__ void k_count(const int* __restrict__ dst, int E, int* __restrict__ cnt)
{
  int e = blockIdx.x * blockDim.x + threadIdx.x;
  if (e < E) atomicAdd(&cnt[dst[e]], 1);
}

__global__ void k_scan_build(const int* __restrict__ cnt, int n,
                             int* __restrict__ offs, int* __restrict__ cursor,
                             float* __restrict__ dinv)
{
  __shared__ int part[1024];
  const int tid = threadIdx.x;
  const int per = (n + 1023) >> 10;
  const int base = tid * per;
  int s = 0;
  for (int i = 0; i < per; ++i) { int idx = base + i; if (idx < n) s += cnt[idx]; }
  part[tid] = s;
  __syncthreads();
  for (int off = 1; off < 1024; off <<= 1) {
    int v = 0;
    if (tid >= off) v = part[tid - off];
    __syncthreads();
    part[tid] += v;
    __syncthreads();
  }
  int run = part[tid] - s;
  for (int i = 0; i < per; ++i) {
    int idx = base + i;
    if (idx < n) {
      offs[idx] = run; cursor[idx] = run;
      int c = cnt[idx];
      dinv[idx] = 1.0f / sqrtf((float)(c + 1));
      run += c;
    }
  }
}

__global__ void k_fill(const int* __restrict__ src, const int* __restrict__ dst,
                       int E, int* __restrict__ cursor, int* __restrict__ csr)
{
  int e = blockIdx.x * blockDim.x + threadIdx.x;
  if (e < E) {
    int d = dst[e];
    int pos = atomicAdd(&cursor[d], 1);
    csr[pos] = src[e];
  }
}

// CSR aggregate for layer1 (FD=64) + bias/relu, FUSED with xw2 = g1 @ W2.
__global__ void k_agg_x2(const float* __restrict__ xw, const int* __restrict__ offs,
                         const int* __restrict__ cnt, const int* __restrict__ csr,
                         const float* __restrict__ dinv, const float* __restrict__ b,
                         const float* __restrict__ W2,
                         float* __restrict__ g1out, float* __restrict__ xw2out, int n)
{
  __shared__ float sg[4][GG1];
  const int nd   = threadIdx.x >> 6;
  const int lane = threadIdx.x & 63;
  const int node = blockIdx.x * 4 + nd;
  if (node < n) {
    const float di = dinv[node];
    float acc = xw[(size_t)node*GG1 + lane] * di * di;
    const int s0 = offs[node], e0 = s0 + cnt[node];
    for (int p = s0; p < e0; ++p) {
      int s = csr[p];
      acc = fmaf(xw[(size_t)s*GG1 + lane], dinv[s] * di, acc);
    }
    float val = fmaxf(acc + b[lane], 0.0f);
    g1out[(size_t)node*GG1 + lane] = val;
    sg[nd][lane] = val;
  }
  __syncthreads();
  if (node < n && lane < GG2) {
    float a2 = 0.0f;
#pragma unroll
    for (int k = 0; k < GG1; ++k) a2 = fmaf(sg[nd][k], W2[k*GG2 + lane], a2);
    xw2out[(size_t)node*GG2 + lane] = a2;
  }
}

template <int FD>
__global__ void k_agg(const float* __restrict__ xw, const int* __restrict__ offs,
                      const int* __restrict__ cnt, const int* __restrict__ csr,
                      const float* __restrict__ dinv, const float* __restrict__ b,
                      float* __restrict__ out, int n)
{
  int gidx = blockIdx.x * blockDim.x + threadIdx.x;
  int node = gidx / FD, lane = gidx % FD;
  if (node >= n) return;
  const float di = dinv[node];
  float acc = xw[(size_t)node*FD + lane] * di * di;
  const int s0 = offs[node], e0 = s0 + cnt[node];
  for (int p = s0; p < e0; ++p) {
    int s = csr[p];
    acc = fmaf(xw[(size_t)s*FD + lane], dinv[s] * di, acc);
  }
  out[(size_t)node*FD + lane] = fmaxf(acc + b[lane], 0.0f);
}

__global__ void k_fc(const float* __restrict__ g2, const int* __restrict__ sid,
                     const float* __restrict__ fcW, const float* __restrict__ fcb,
                     float* __restrict__ out, int n)
{
  int i = blockIdx.x * blockDim.x + threadIdx.x;
  if (i >= n) return;
  const float* row = g2 + (size_t)sid[i] * GG2;
  float acc = fcb[0];
#pragma unroll
  for (int f = 0; f < GG2; ++f) acc = fmaf(row[f], fcW[f], acc);
  out[i] = acc;
}

// ---------------------------------------------------------------------------
extern "C" void kernel_launch(void* const* d_in, const int* in_sizes, int n_in,
                              void* d_out, int out_size, void* d_ws, size_t ws_size,
                              hipStream_t stream)
{
  const float* x    = (const float*)d_in[0];
  const int*   sid  = (const int*)  d_in[1];
  const int*   eidx = (const int*)  d_in[2];
  const float* Wih0 = (const float*)d_in[3];
  const float* Whh0 = (const float*)d_in[4];
  const float* bih0 = (const float*)d_in[5];
  const float* bhh0 = (const float*)d_in[6];
  const float* Wih1 = (const float*)d_in[7];
  const float* Whh1 = (const float*)d_in[8];
  const float* bih1 = (const float*)d_in[9];
  const float* bhh1 = (const float*)d_in[10];
  const float* g1W  = (const float*)d_in[11];
  const float* g1b  = (const float*)d_in[12];
  const float* g2W  = (const float*)d_in[13];
  const float* g2b  = (const float*)d_in[14];
  const float* fcW  = (const float*)d_in[15];
  const float* fcb  = (const float*)d_in[16];

  const int n = in_sizes[1];
  const int E = in_sizes[2] / 2;
  float* out = (float*)d_out;

  char* w = (char*)d_ws;
  auto carve = [&](size_t bytes) -> void* {
    void* p = (void*)w; w += (bytes + 255) & ~(size_t)255; return p;
  };
  int*   cnt    = (int*)  carve((size_t)n * 4);
  int*   offs   = (int*)  carve((size_t)n * 4);
  int*   cursor = (int*)  carve((size_t)n * 4);
  float* dinv   = (float*)carve((size_t)n * 4);
  int*   csr    = (int*)  carve((size_t)E * 4);
  float* xw1    = (float*)carve((size_t)n * GG1 * 4);
  float* g1     = (float*)carve((size_t)n * GG1 * 4);
  float* xw2    = (float*)carve((size_t)n * GG2 * 4);
  float* g2     = (float*)carve((size_t)n * GG2 * 4);

  const int* src = eidx;
  const int* dst = eidx + E;

  lstm_mfma<<<(n + NN - 1) / NN, 1024, 0, stream>>>(x, Wih0, Whh0, bih0, bhh0,
                                                    Wih1, Whh1, bih1, bhh1,
                                                    g1W, xw1, n);

  hipMemsetAsync(cnt, 0, (size_t)n * 4, stream);
  k_count<<<(E + 255) / 256, 256, 0, stream>>>(dst, E, cnt);
  k_scan_build<<<1, 1024, 0, stream>>>(cnt, n, offs, cursor, dinv);
  k_fill<<<(E + 255) / 256, 256, 0, stream>>>(src, dst, E, cursor, csr);

  k_agg_x2<<<(n + 3) / 4, 256, 0, stream>>>(xw1, offs, cnt, csr, dinv, g1b, g2W, g1, xw2, n);

  k_agg<GG2><<<((size_t)n * GG2 + 255) / 256, 256, 0, stream>>>(xw2, offs, cnt, csr, dinv, g2b, g2, n);

  k_fc<<<(n + 255) / 256, 256, 0, stream>>>(g2, sid, fcW, fcb, out, n);
}

// Round 16
// 660.500 us; speedup vs baseline: 1.0364x; 1.0258x over previous
//
#include <hip/hip_runtime.h>
#include <math.h>

#define TT 64
#define FF 32
#define HH 64
#define NN 16     // nodes per block
#define GG1 64
#define GG2 32

typedef float f32x4 __attribute__((ext_vector_type(4)));
typedef short bf16x8 __attribute__((ext_vector_type(8)));

__device__ __forceinline__ float fexp2(float x){ return __builtin_amdgcn_exp2f(x); }
__device__ __forceinline__ float frcp (float x){ return __builtin_amdgcn_rcpf(x); }
#define L2E 1.442695041f
__device__ __forceinline__ float sigm_nb(float v, float nb){
  return frcp(1.0f + fexp2(fmaf(v, -L2E, nb)));
}
__device__ __forceinline__ float tanh_b(float v, float b2){
  return fmaf(-2.0f, frcp(1.0f + fexp2(fmaf(v, 2.0f*L2E, b2))), 1.0f);
}
__device__ __forceinline__ float tanh0(float v){
  return fmaf(-2.0f, frcp(1.0f + fexp2(2.0f*L2E*v)), 1.0f);
}

// lane <-> lane^8 exchange within rows of 16 lanes (DPP row_ror:8, VALU pipe)
__device__ __forceinline__ float xor8(float v){
  int a = __builtin_bit_cast(int, v);
  int b = __builtin_amdgcn_update_dpp(0, a, 0x128, 0xF, 0xF, true);
  return __builtin_bit_cast(float, b);
}

__device__ __forceinline__ unsigned short bf16rn(float x){
  unsigned u = __builtin_bit_cast(unsigned, x);
  return (unsigned short)((u + 0x7FFFu + ((u >> 16) & 1u)) >> 16);
}
__device__ __forceinline__ void split2(float x, unsigned short& h, unsigned short& l){
  unsigned u = __builtin_bit_cast(unsigned, x);
  unsigned hr = (u + 0x7FFFu + ((u >> 16) & 1u)) & 0xFFFF0000u;
  h = (unsigned short)(hr >> 16);
  l = bf16rn(x - __builtin_bit_cast(float, hr));
}
// packed split of 2 values via v_cvt_pk_bf16_f32 (HW RNE)
__device__ __forceinline__ void split_pk(float a, float b, unsigned& hi2, unsigned& lo2){
  asm("v_cvt_pk_bf16_f32 %0, %1, %2" : "=v"(hi2) : "v"(a), "v"(b));
  float ha = __builtin_bit_cast(float, hi2 << 16);
  float hb = __builtin_bit_cast(float, hi2 & 0xFFFF0000u);
  float la = a - ha, lb = b - hb;
  asm("v_cvt_pk_bf16_f32 %0, %1, %2" : "=v"(lo2) : "v"(la), "v"(lb));
}

#define PIN(v) asm volatile("" : "+v"(v))
#define MFMA(acc, a, b) (acc) = __builtin_amdgcn_mfma_f32_16x16x32_bf16((a), (b), (acc), 0, 0, 0)

__device__ __forceinline__ void wsplit(const float* p, bf16x8& hi, bf16x8& lo){
  float4 a = *(const float4*)p;
  float4 b = *(const float4*)(p + 4);
  unsigned short h, s;
  split2(a.x,h,s); hi[0]=(short)h; lo[0]=(short)s;
  split2(a.y,h,s); hi[1]=(short)h; lo[1]=(short)s;
  split2(a.z,h,s); hi[2]=(short)h; lo[2]=(short)s;
  split2(a.w,h,s); hi[3]=(short)h; lo[3]=(short)s;
  split2(b.x,h,s); hi[4]=(short)h; lo[4]=(short)s;
  split2(b.y,h,s); hi[5]=(short)h; lo[5]=(short)s;
  split2(b.z,h,s); hi[6]=(short)h; lo[6]=(short)s;
  split2(b.w,h,s); hi[7]=(short)h; lo[7]=(short)s;
}

// ---------------------------------------------------------------------------
// Fused 2-layer LSTM on MFMA, bf16 hi/lo emulated-fp32 (3-pass), in-register
// DPP combine, role-split 16-wave block, dephased 2-phase schedule
// (round-13/15 structure). ROUND-16 delta: t-loop explicitly unrolled x2
// with phase p in {0,1} compile-time, so all double-buffer LDS addresses are
// loop-invariant (hoistable) and x staging is a pointer bump, not a 64-bit
// address recompute — attacks the ~1200 cyc/SIMD/t of addressing VALU fat.
// ---------------------------------------------------------------------------
__global__ __launch_bounds__(1024, 4)
void lstm_mfma(const float* __restrict__ x,
    const float* __restrict__ Wih0, const float* __restrict__ Whh0,
    const float* __restrict__ bih0, const float* __restrict__ bhh0,
    const float* __restrict__ Wih1, const float* __restrict__ Whh1,
    const float* __restrict__ bih1, const float* __restrict__ bhh1,
    const float* __restrict__ g1W, float* __restrict__ xw1out, int n)
{
  const int tid  = threadIdx.x;
  const int wv   = tid >> 6;     // wave 0..15
  const int role = wv >> 3;      // 0 = layer0 waves, 1 = layer1 waves
  const int w    = wv & 7;       // col-group within role
  const int l    = tid & 63;
  const int lr   = l & 15;       // A row (node) / B,D col-slot
  const int lg   = l >> 4;       // k-group 0..3
  const int nA   = blockIdx.x * NN;
  int avail = n - nA; if (avail > NN) avail = NN;

  __shared__ short Ax[2][2][16][40];   // [buf][hi/lo][node][f]
  __shared__ short H0[2][2][16][88];   // [buf][hi/lo][node][m]
  __shared__ short H1[2][16][88];      // [hi/lo][node][m] single time-buffer
  __shared__ float hf[16][64];         // final h1 (fp32) for xw1 fusion

  const int jm   = lr & 7;
  const bool lo8 = (lr < 8);
  const int col0 = lo8 ? (8*w + jm) : (64  + 8*w + jm);       // i | f
  const int col1 = lo8 ? (128 + 8*w + jm) : (192 + 8*w + jm); // g | o

  // ---- role-dependent weights -> split register fragments ----
  bf16x8 Wh[2][4], Wl[2][4];
  if (role == 0){
#pragma unroll
    for (int h = 0; h < 2; ++h){
      const int col = h ? col1 : col0;
      wsplit(Wih0 + col*FF + 8*lg,      Wh[h][0], Wl[h][0]);
      wsplit(Whh0 + col*HH + 8*lg,      Wh[h][1], Wl[h][1]);
      wsplit(Whh0 + col*HH + 32 + 8*lg, Wh[h][2], Wl[h][2]);
      Wh[h][3] = Wh[h][2]; Wl[h][3] = Wl[h][2];
    }
  } else {
#pragma unroll
    for (int h = 0; h < 2; ++h){
      const int col = h ? col1 : col0;
      wsplit(Wih1 + col*HH + 8*lg,      Wh[h][0], Wl[h][0]);
      wsplit(Wih1 + col*HH + 32 + 8*lg, Wh[h][1], Wl[h][1]);
      wsplit(Whh1 + col*HH + 8*lg,      Wh[h][2], Wl[h][2]);
      wsplit(Whh1 + col*HH + 32 + 8*lg, Wh[h][3], Wl[h][3]);
    }
  }
#pragma unroll
  for (int h = 0; h < 2; ++h)
#pragma unroll
    for (int k = 0; k < 4; ++k){ PIN(Wh[h][k]); PIN(Wl[h][k]); }

  // ---- per-lane pre-scaled gate biases for this role's layer, col m ----
  const int m = 8*w + jm;
  const float* bi = role ? bih1 : bih0;
  const float* bh = role ? bhh1 : bhh0;
  const float nb_i = -L2E      * (bi[m      ] + bh[m      ]);
  const float nb_f = -L2E      * (bi[m +  64] + bh[m +  64]);
  const float b2_g =  2.0f*L2E * (bi[m + 128] + bh[m + 128]);
  const float nb_o = -L2E      * (bi[m + 192] + bh[m + 192]);

  // ---- zero h planes; stage x(0) ----
  const int xnd = tid >> 5, xf = tid & 31;    // x staging role (tid<512)
  {
    short* p0 = &H0[0][0][0][0];
    for (int i = tid; i < 2*2*16*88; i += 1024) p0[i] = 0;
    short* p1 = &H1[0][0][0];
    for (int i = tid; i < 2*16*88; i += 1024) p1[i] = 0;
    if (tid < 512){
      float v = (xnd < avail) ? x[((size_t)(nA+xnd)*TT + 0)*FF + xf] : 0.0f;
      unsigned short hh, hl; split2(v, hh, hl);
      Ax[0][0][xnd][xf] = (short)hh;
      Ax[0][1][xnd][xf] = (short)hl;
    }
  }
  // hoisted per-thread x pointer: points at x(t=1); advanced FF per timestep
  const float* xp = x + ((size_t)(nA + xnd)*TT + 1)*FF + xf;
  const bool xok = (role == 0) && (xnd < avail);

  const int na = 4*lg + (lo8 ? 0 : 2);
  const int nb = na + 1;
  float ca = 0.0f, cb = 0.0f;
  f32x4 D0 = {0.f,0.f,0.f,0.f}, D1 = {0.f,0.f,0.f,0.f};
  const f32x4 Z = {0.f, 0.f, 0.f, 0.f};
  __syncthreads();

  for (int tt = 0; tt < TT; tt += 2){
#pragma unroll
    for (int p = 0; p < 2; ++p){
      const int t   = tt + p;
      const int rd0 = p ^ 1;     // compile-time buffer indices
      const int wr0 = p;
      f32x4 A0, A1;
      float xv = 0.0f;

      // ================== PHASE 1: L0 MFMA || L1 combine ==================
      if (role == 0){
        const int tp = t + 1;
        if (tp < TT && xok) xv = *xp;

        bf16x8 axh  = *(const bf16x8*)&Ax[p][0][lr][8*lg];
        bf16x8 axl  = *(const bf16x8*)&Ax[p][1][lr][8*lg];
        bf16x8 h0ah = *(const bf16x8*)&H0[rd0][0][lr][8*lg];
        bf16x8 h0al = *(const bf16x8*)&H0[rd0][1][lr][8*lg];
        bf16x8 h0bh = *(const bf16x8*)&H0[rd0][0][lr][32+8*lg];
        bf16x8 h0bl = *(const bf16x8*)&H0[rd0][1][lr][32+8*lg];

        __builtin_amdgcn_s_setprio(1);
        A0 = __builtin_amdgcn_mfma_f32_16x16x32_bf16(axl, Wh[0][0], Z, 0, 0, 0);
        A1 = __builtin_amdgcn_mfma_f32_16x16x32_bf16(axl, Wh[1][0], Z, 0, 0, 0);
        MFMA(A0, axh,  Wl[0][0]); MFMA(A0, axh,  Wh[0][0]);
        MFMA(A1, axh,  Wl[1][0]); MFMA(A1, axh,  Wh[1][0]);
        MFMA(A0, h0al, Wh[0][1]); MFMA(A0, h0ah, Wl[0][1]); MFMA(A0, h0ah, Wh[0][1]);
        MFMA(A1, h0al, Wh[1][1]); MFMA(A1, h0ah, Wl[1][1]); MFMA(A1, h0ah, Wh[1][1]);
        MFMA(A0, h0bl, Wh[0][2]); MFMA(A0, h0bh, Wl[0][2]); MFMA(A0, h0bh, Wh[0][2]);
        MFMA(A1, h0bl, Wh[1][2]); MFMA(A1, h0bh, Wl[1][2]); MFMA(A1, h0bh, Wh[1][2]);
        __builtin_amdgcn_s_setprio(0);
      }
      else if (t >= 2){
        // combine C1(t-2) from D0,D1 -> h1(t-2)
        f32x4 s0, s1;
        s0[0]=xor8(D0[0]); s0[1]=xor8(D0[1]); s0[2]=xor8(D0[2]); s0[3]=xor8(D0[3]);
        s1[0]=xor8(D1[0]); s1[1]=xor8(D1[1]); s1[2]=xor8(D1[2]); s1[3]=xor8(D1[3]);
        float gi_a = lo8 ? D0[0] : s0[2],  gi_b = lo8 ? D0[1] : s0[3];
        float gf_a = lo8 ? s0[0] : D0[2],  gf_b = lo8 ? s0[1] : D0[3];
        float gg_a = lo8 ? D1[0] : s1[2],  gg_b = lo8 ? D1[1] : s1[3];
        float go_a = lo8 ? s1[0] : D1[2],  go_b = lo8 ? s1[1] : D1[3];
        ca = sigm_nb(gf_a, nb_f)*ca + sigm_nb(gi_a, nb_i)*tanh_b(gg_a, b2_g);
        float ha = sigm_nb(go_a, nb_o)*tanh0(ca);
        cb = sigm_nb(gf_b, nb_f)*cb + sigm_nb(gi_b, nb_i)*tanh_b(gg_b, b2_g);
        float hb = sigm_nb(go_b, nb_o)*tanh0(cb);
        unsigned hi2, lo2; split_pk(ha, hb, hi2, lo2);
        H1[0][na][m] = (short)(hi2 & 0xFFFF);
        H1[0][nb][m] = (short)(hi2 >> 16);
        H1[1][na][m] = (short)(lo2 & 0xFFFF);
        H1[1][nb][m] = (short)(lo2 >> 16);
      }
      __syncthreads();

      // ================== PHASE 2: L0 combine || L1 MFMA ==================
      if (role == 0){
        f32x4 s0, s1;
        s0[0]=xor8(A0[0]); s0[1]=xor8(A0[1]); s0[2]=xor8(A0[2]); s0[3]=xor8(A0[3]);
        s1[0]=xor8(A1[0]); s1[1]=xor8(A1[1]); s1[2]=xor8(A1[2]); s1[3]=xor8(A1[3]);
        float gi_a = lo8 ? A0[0] : s0[2],  gi_b = lo8 ? A0[1] : s0[3];
        float gf_a = lo8 ? s0[0] : A0[2],  gf_b = lo8 ? s0[1] : A0[3];
        float gg_a = lo8 ? A1[0] : s1[2],  gg_b = lo8 ? A1[1] : s1[3];
        float go_a = lo8 ? s1[0] : A1[2],  go_b = lo8 ? s1[1] : A1[3];
        ca = sigm_nb(gf_a, nb_f)*ca + sigm_nb(gi_a, nb_i)*tanh_b(gg_a, b2_g);
        float ha = sigm_nb(go_a, nb_o)*tanh0(ca);
        cb = sigm_nb(gf_b, nb_f)*cb + sigm_nb(gi_b, nb_i)*tanh_b(gg_b, b2_g);
        float hb = sigm_nb(go_b, nb_o)*tanh0(cb);
        unsigned hi2, lo2; split_pk(ha, hb, hi2, lo2);
        H0[wr0][0][na][m] = (short)(hi2 & 0xFFFF);
        H0[wr0][0][nb][m] = (short)(hi2 >> 16);
        H0[wr0][1][na][m] = (short)(lo2 & 0xFFFF);
        H0[wr0][1][nb][m] = (short)(lo2 >> 16);
        // stage x(t+1) into buffer p^1 (pointer bump addressing)
        const int tp = t + 1;
        if (tp < TT && tid < 512){
          unsigned short hh, hl; split2(xv, hh, hl);
          Ax[p^1][0][xnd][xf] = (short)hh;
          Ax[p^1][1][xnd][xf] = (short)hl;
        }
      }
      else if (t >= 1){
        // MFMA G1(t-1): reads h0(t-1) [buf rd0] and h1(t-2)
        bf16x8 h0ah = *(const bf16x8*)&H0[rd0][0][lr][8*lg];
        bf16x8 h0al = *(const bf16x8*)&H0[rd0][1][lr][8*lg];
        bf16x8 h0bh = *(const bf16x8*)&H0[rd0][0][lr][32+8*lg];
        bf16x8 h0bl = *(const bf16x8*)&H0[rd0][1][lr][32+8*lg];

        __builtin_amdgcn_s_setprio(1);
        D0 = __builtin_amdgcn_mfma_f32_16x16x32_bf16(h0al, Wh[0][0], Z, 0, 0, 0);
        D1 = __builtin_amdgcn_mfma_f32_16x16x32_bf16(h0al, Wh[1][0], Z, 0, 0, 0);
        MFMA(D0, h0ah, Wl[0][0]); MFMA(D0, h0ah, Wh[0][0]);
        MFMA(D1, h0ah, Wl[1][0]); MFMA(D1, h0ah, Wh[1][0]);
        MFMA(D0, h0bl, Wh[0][1]); MFMA(D0, h0bh, Wl[0][1]); MFMA(D0, h0bh, Wh[0][1]);
        MFMA(D1, h0bl, Wh[1][1]); MFMA(D1, h0bh, Wl[1][1]); MFMA(D1, h0bh, Wh[1][1]);
        bf16x8 h1ah = *(const bf16x8*)&H1[0][lr][8*lg];
        bf16x8 h1al = *(const bf16x8*)&H1[1][lr][8*lg];
        bf16x8 h1bh = *(const bf16x8*)&H1[0][lr][32+8*lg];
        bf16x8 h1bl = *(const bf16x8*)&H1[1][lr][32+8*lg];
        MFMA(D0, h1al, Wh[0][2]); MFMA(D0, h1ah, Wl[0][2]); MFMA(D0, h1ah, Wh[0][2]);
        MFMA(D1, h1al, Wh[1][2]); MFMA(D1, h1ah, Wl[1][2]); MFMA(D1, h1ah, Wh[1][2]);
        MFMA(D0, h1bl, Wh[0][3]); MFMA(D0, h1bh, Wl[0][3]); MFMA(D0, h1bh, Wh[0][3]);
        MFMA(D1, h1bl, Wh[1][3]); MFMA(D1, h1bh, Wl[1][3]); MFMA(D1, h1bh, Wh[1][3]);
        __builtin_amdgcn_s_setprio(0);
      }
      __syncthreads();
      xp += FF;   // advance to next timestep's x
    }
  }

  // ================== epilogue ==================
  if (role == 1){
    f32x4 s0, s1;
    s0[0]=xor8(D0[0]); s0[1]=xor8(D0[1]); s0[2]=xor8(D0[2]); s0[3]=xor8(D0[3]);
    s1[0]=xor8(D1[0]); s1[1]=xor8(D1[1]); s1[2]=xor8(D1[2]); s1[3]=xor8(D1[3]);
    float gi_a = lo8 ? D0[0] : s0[2],  gi_b = lo8 ? D0[1] : s0[3];
    float gf_a = lo8 ? s0[0] : D0[2],  gf_b = lo8 ? s0[1] : D0[3];
    float gg_a = lo8 ? D1[0] : s1[2],  gg_b = lo8 ? D1[1] : s1[3];
    float go_a = lo8 ? s1[0] : D1[2],  go_b = lo8 ? s1[1] : D1[3];
    ca = sigm_nb(gf_a, nb_f)*ca + sigm_nb(gi_a, nb_i)*tanh_b(gg_a, b2_g);
    float ha = sigm_nb(go_a, nb_o)*tanh0(ca);
    cb = sigm_nb(gf_b, nb_f)*cb + sigm_nb(gi_b, nb_i)*tanh_b(gg_b, b2_g);
    float hb = sigm_nb(go_b, nb_o)*tanh0(cb);
    unsigned hi2, lo2; split_pk(ha, hb, hi2, lo2);
    H1[0][na][m] = (short)(hi2 & 0xFFFF);
    H1[0][nb][m] = (short)(hi2 >> 16);
    H1[1][na][m] = (short)(lo2 & 0xFFFF);
    H1[1][nb][m] = (short)(lo2 >> 16);
  }
  __syncthreads();
  if (role == 1){
    const int rd0 = (TT-1) & 1;      // h0(TT-1)
    bf16x8 h0ah = *(const bf16x8*)&H0[rd0][0][lr][8*lg];
    bf16x8 h0al = *(const bf16x8*)&H0[rd0][1][lr][8*lg];
    bf16x8 h0bh = *(const bf16x8*)&H0[rd0][0][lr][32+8*lg];
    bf16x8 h0bl = *(const bf16x8*)&H0[rd0][1][lr][32+8*lg];
    bf16x8 h1ah = *(const bf16x8*)&H1[0][lr][8*lg];
    bf16x8 h1al = *(const bf16x8*)&H1[1][lr][8*lg];
    bf16x8 h1bh = *(const bf16x8*)&H1[0][lr][32+8*lg];
    bf16x8 h1bl = *(const bf16x8*)&H1[1][lr][32+8*lg];
    f32x4 E0 = __builtin_amdgcn_mfma_f32_16x16x32_bf16(h0al, Wh[0][0], Z, 0, 0, 0);
    f32x4 E1 = __builtin_amdgcn_mfma_f32_16x16x32_bf16(h0al, Wh[1][0], Z, 0, 0, 0);
    MFMA(E0, h0ah, Wl[0][0]); MFMA(E0, h0ah, Wh[0][0]);
    MFMA(E1, h0ah, Wl[1][0]); MFMA(E1, h0ah, Wh[1][0]);
    MFMA(E0, h0bl, Wh[0][1]); MFMA(E0, h0bh, Wl[0][1]); MFMA(E0, h0bh, Wh[0][1]);
    MFMA(E1, h0bl, Wh[1][1]); MFMA(E1, h0bh, Wl[1][1]); MFMA(E1, h0bh, Wh[1][1]);
    MFMA(E0, h1al, Wh[0][2]); MFMA(E0, h1ah, Wl[0][2]); MFMA(E0, h1ah, Wh[0][2]);
    MFMA(E1, h1al, Wh[1][2]); MFMA(E1, h1ah, Wl[1][2]); MFMA(E1, h1ah, Wh[1][2]);
    MFMA(E0, h1bl, Wh[0][3]); MFMA(E0, h1bh, Wl[0][3]); MFMA(E0, h1bh, Wh[0][3]);
    MFMA(E1, h1bl, Wh[1][3]); MFMA(E1, h1bh, Wl[1][3]); MFMA(E1, h1bh, Wh[1][3]);

    f32x4 s0, s1;
    s0[0]=xor8(E0[0]); s0[1]=xor8(E0[1]); s0[2]=xor8(E0[2]); s0[3]=xor8(E0[3]);
    s1[0]=xor8(E1[0]); s1[1]=xor8(E1[1]); s1[2]=xor8(E1[2]); s1[3]=xor8(E1[3]);
    float gi_a = lo8 ? E0[0] : s0[2],  gi_b = lo8 ? E0[1] : s0[3];
    float gf_a = lo8 ? s0[0] : E0[2],  gf_b = lo8 ? s0[1] : E0[3];
    float gg_a = lo8 ? E1[0] : s1[2],  gg_b = lo8 ? E1[1] : s1[3];
    float go_a = lo8 ? s1[0] : E1[2],  go_b = lo8 ? s1[1] : E1[3];
    ca = sigm_nb(gf_a, nb_f)*ca + sigm_nb(gi_a, nb_i)*tanh_b(gg_a, b2_g);
    float ha = sigm_nb(go_a, nb_o)*tanh0(ca);
    cb = sigm_nb(gf_b, nb_f)*cb + sigm_nb(gi_b, nb_i)*tanh_b(gg_b, b2_g);
    float hb = sigm_nb(go_b, nb_o)*tanh0(cb);
    hf[na][m] = ha;
    hf[nb][m] = hb;
  }
  __syncthreads();

  // ---- fused xw1 = h1_final @ g1W (one output per thread; wave==node) ----
  {
    const int node = tid >> 6;
    const int col  = tid & 63;
    if (node < avail){
      float acc = 0.0f;
#pragma unroll
      for (int k = 0; k < HH; ++k)
        acc = fmaf(hf[node][k], g1W[k*GG1 + col], acc);
      xw1out[(size_t)(nA + node)*GG1 + col] = acc;
    }
  }
}

// ---------------------------------------------------------------------------
// GCN support kernels
// ---------------------------------------------------------------------------
__global__ void k_count(const int* __restrict__ dst, int E, int* __restrict__ cnt)
{
  int e = blockIdx.x * blockDim.x + threadIdx.x;
  if (e < E) atomicAdd(&cnt[dst[e]], 1);
}

__global__ void k_scan_build(const int* __restrict__ cnt, int n,
                             int* __restrict__ offs, int* __restrict__ cursor,
                             float* __restrict__ dinv)
{
  __shared__ int part[1024];
  const int tid = threadIdx.x;
  const int per = (n + 1023) >> 10;
  const int base = tid * per;
  int s = 0;
  for (int i = 0; i < per; ++i) { int idx = base + i; if (idx < n) s += cnt[idx]; }
  part[tid] = s;
  __syncthreads();
  for (int off = 1; off < 1024; off <<= 1) {
    int v = 0;
    if (tid >= off) v = part[tid - off];
    __syncthreads();
    part[tid] += v;
    __syncthreads();
  }
  int run = part[tid] - s;
  for (int i = 0; i < per; ++i) {
    int idx = base + i;
    if (idx < n) {
      offs[idx] = run; cursor[idx] = run;
      int c = cnt[idx];
      dinv[idx] = 1.0f / sqrtf((float)(c + 1));
      run += c;
    }
  }
}

__global__ void k_fill(const int* __restrict__ src, const int* __restrict__ dst,
                       int E, int* __restrict__ cursor, int* __restrict__ csr)
{
  int e = blockIdx.x * blockDim.x + threadIdx.x;
  if (e < E) {
    int d = dst[e];
    int pos = atomicAdd(&cursor[d], 1);
    csr[pos] = src[e];
  }
}

// CSR aggregate for layer1 (FD=64) + bias/relu, FUSED with xw2 = g1 @ W2.
__global__ void k_agg_x2(const float* __restrict__ xw, const int* __restrict__ offs,
                         const int* __restrict__ cnt, const int* __restrict__ csr,
                         const float* __restrict__ dinv, const float* __restrict__ b,
                         const float* __restrict__ W2,
                         float* __restrict__ g1out, float* __restrict__ xw2out, int n)
{
  __shared__ float sg[4][GG1];
  const int nd   = threadIdx.x >> 6;
  const int lane = threadIdx.x & 63;
  const int node = blockIdx.x * 4 + nd;
  if (node < n) {
    const float di = dinv[node];
    float acc = xw[(size_t)node*GG1 + lane] * di * di;
    const int s0 = offs[node], e0 = s0 + cnt[node];
    for (int p = s0; p < e0; ++p) {
      int s = csr[p];
      acc = fmaf(xw[(size_t)s*GG1 + lane], dinv[s] * di, acc);
    }
    float val = fmaxf(acc + b[lane], 0.0f);
    g1out[(size_t)node*GG1 + lane] = val;
    sg[nd][lane] = val;
  }
  __syncthreads();
  if (node < n && lane < GG2) {
    float a2 = 0.0f;
#pragma unroll
    for (int k = 0; k < GG1; ++k) a2 = fmaf(sg[nd][k], W2[k*GG2 + lane], a2);
    xw2out[(size_t)node*GG2 + lane] = a2;
  }
}

template <int FD>
__global__ void k_agg(const float* __restrict__ xw, const int* __restrict__ offs,
                      const int* __restrict__ cnt, const int* __restrict__ csr,
                      const float* __restrict__ dinv, const float* __restrict__ b,
                      float* __restrict__ out, int n)
{
  int gidx = blockIdx.x * blockDim.x + threadIdx.x;
  int node = gidx / FD, lane = gidx % FD;
  if (node >= n) return;
  const float di = dinv[node];
  float acc = xw[(size_t)node*FD + lane] * di * di;
  const int s0 = offs[node], e0 = s0 + cnt[node];
  for (int p = s0; p < e0; ++p) {
    int s = csr[p];
    acc = fmaf(xw[(size_t)s*FD + lane], dinv[s] * di, acc);
  }
  out[(size_t)node*FD + lane] = fmaxf(acc + b[lane], 0.0f);
}

__global__ void k_fc(const float* __restrict__ g2, const int* __restrict__ sid,
                     const float* __restrict__ fcW, const float* __restrict__ fcb,
                     float* __restrict__ out, int n)
{
  int i = blockIdx.x * blockDim.x + threadIdx.x;
  if (i >= n) return;
  const float* row = g2 + (size_t)sid[i] * GG2;
  float acc = fcb[0];
#pragma unroll
  for (int f = 0; f < GG2; ++f) acc = fmaf(row[f], fcW[f], acc);
  out[i] = acc;
}

// ---------------------------------------------------------------------------
extern "C" void kernel_launch(void* const* d_in, const int* in_sizes, int n_in,
                              void* d_out, int out_size, void* d_ws, size_t ws_size,
                              hipStream_t stream)
{
  const float* x    = (const float*)d_in[0];
  const int*   sid  = (const int*)  d_in[1];
  const int*   eidx = (const int*)  d_in[2];
  const float* Wih0 = (const float*)d_in[3];
  const float* Whh0 = (const float*)d_in[4];
  const float* bih0 = (const float*)d_in[5];
  const float* bhh0 = (const float*)d_in[6];
  const float* Wih1 = (const float*)d_in[7];
  const float* Whh1 = (const float*)d_in[8];
  const float* bih1 = (const float*)d_in[9];
  const float* bhh1 = (const float*)d_in[10];
  const float* g1W  = (const float*)d_in[11];
  const float* g1b  = (const float*)d_in[12];
  const float* g2W  = (const float*)d_in[13];
  const float* g2b  = (const float*)d_in[14];
  const float* fcW  = (const float*)d_in[15];
  const float* fcb  = (const float*)d_in[16];

  const int n = in_sizes[1];
  const int E = in_sizes[2] / 2;
  float* out = (float*)d_out;

  char* w = (char*)d_ws;
  auto carve = [&](size_t bytes) -> void* {
    void* p = (void*)w; w += (bytes + 255) & ~(size_t)255; return p;
  };
  int*   cnt    = (int*)  carve((size_t)n * 4);
  int*   offs   = (int*)  carve((size_t)n * 4);
  int*   cursor = (int*)  carve((size_t)n * 4);
  float* dinv   = (float*)carve((size_t)n * 4);
  int*   csr    = (int*)  carve((size_t)E * 4);
  float* xw1    = (float*)carve((size_t)n * GG1 * 4);
  float* g1     = (float*)carve((size_t)n * GG1 * 4);
  float* xw2    = (float*)carve((size_t)n * GG2 * 4);
  float* g2     = (float*)carve((size_t)n * GG2 * 4);

  const int* src = eidx;
  const int* dst = eidx + E;

  lstm_mfma<<<(n + NN - 1) / NN, 1024, 0, stream>>>(x, Wih0, Whh0, bih0, bhh0,
                                                    Wih1, Whh1, bih1, bhh1,
                                                    g1W, xw1, n);

  hipMemsetAsync(cnt, 0, (size_t)n * 4, stream);
  k_count<<<(E + 255) / 256, 256, 0, stream>>>(dst, E, cnt);
  k_scan_build<<<1, 1024, 0, stream>>>(cnt, n, offs, cursor, dinv);
  k_fill<<<(E + 255) / 256, 256, 0, stream>>>(src, dst, E, cursor, csr);

  k_agg_x2<<<(n + 3) / 4, 256, 0, stream>>>(xw1, offs, cnt, csr, dinv, g1b, g2W, g1, xw2, n);

  k_agg<GG2><<<((size_t)n * GG2 + 255) / 256, 256, 0, stream>>>(xw2, offs, cnt, csr, dinv, g2b, g2, n);

  k_fc<<<(n + 255) / 256, 256, 0, stream>>>(g2, sid, fcW, fcb, out, n);
}

// Round 17
// 658.539 us; speedup vs baseline: 1.0395x; 1.0030x over previous
//
#include <hip/hip_runtime.h>
#include <math.h>

#define TT 64
#define FF 32
#define HH 64
#define NN 16     // nodes per block
#define GG1 64
#define GG2 32

typedef float f32x4 __attribute__((ext_vector_type(4)));
typedef short bf16x8 __attribute__((ext_vector_type(8)));

__device__ __forceinline__ float fexp2(float x){ return __builtin_amdgcn_exp2f(x); }
__device__ __forceinline__ float frcp (float x){ return __builtin_amdgcn_rcpf(x); }
#define L2E 1.442695041f
__device__ __forceinline__ float sigm_nb(float v, float nb){
  return frcp(1.0f + fexp2(fmaf(v, -L2E, nb)));
}
__device__ __forceinline__ float tanh_b(float v, float b2){
  return fmaf(-2.0f, frcp(1.0f + fexp2(fmaf(v, 2.0f*L2E, b2))), 1.0f);
}
__device__ __forceinline__ float tanh0(float v){
  return fmaf(-2.0f, frcp(1.0f + fexp2(2.0f*L2E*v)), 1.0f);
}

// lane <-> lane^8 exchange within rows of 16 lanes (DPP row_ror:8, VALU pipe)
__device__ __forceinline__ float xor8(float v){
  int a = __builtin_bit_cast(int, v);
  int b = __builtin_amdgcn_update_dpp(0, a, 0x128, 0xF, 0xF, true);
  return __builtin_bit_cast(float, b);
}

__device__ __forceinline__ unsigned short bf16rn(float x){
  unsigned u = __builtin_bit_cast(unsigned, x);
  return (unsigned short)((u + 0x7FFFu + ((u >> 16) & 1u)) >> 16);
}
__device__ __forceinline__ void split2(float x, unsigned short& h, unsigned short& l){
  unsigned u = __builtin_bit_cast(unsigned, x);
  unsigned hr = (u + 0x7FFFu + ((u >> 16) & 1u)) & 0xFFFF0000u;
  h = (unsigned short)(hr >> 16);
  l = bf16rn(x - __builtin_bit_cast(float, hr));
}
// packed split of 2 values via v_cvt_pk_bf16_f32 (HW RNE)
__device__ __forceinline__ void split_pk(float a, float b, unsigned& hi2, unsigned& lo2){
  asm("v_cvt_pk_bf16_f32 %0, %1, %2" : "=v"(hi2) : "v"(a), "v"(b));
  float ha = __builtin_bit_cast(float, hi2 << 16);
  float hb = __builtin_bit_cast(float, hi2 & 0xFFFF0000u);
  float la = a - ha, lb = b - hb;
  asm("v_cvt_pk_bf16_f32 %0, %1, %2" : "=v"(lo2) : "v"(la), "v"(lb));
}

#define PIN(v) asm volatile("" : "+v"(v))
#define MFMA(acc, a, b) (acc) = __builtin_amdgcn_mfma_f32_16x16x32_bf16((a), (b), (acc), 0, 0, 0)

__device__ __forceinline__ void wsplit(const float* p, bf16x8& hi, bf16x8& lo){
  float4 a = *(const float4*)p;
  float4 b = *(const float4*)(p + 4);
  unsigned short h, s;
  split2(a.x,h,s); hi[0]=(short)h; lo[0]=(short)s;
  split2(a.y,h,s); hi[1]=(short)h; lo[1]=(short)s;
  split2(a.z,h,s); hi[2]=(short)h; lo[2]=(short)s;
  split2(a.w,h,s); hi[3]=(short)h; lo[3]=(short)s;
  split2(b.x,h,s); hi[4]=(short)h; lo[4]=(short)s;
  split2(b.y,h,s); hi[5]=(short)h; lo[5]=(short)s;
  split2(b.z,h,s); hi[6]=(short)h; lo[6]=(short)s;
  split2(b.w,h,s); hi[7]=(short)h; lo[7]=(short)s;
}

// ---------------------------------------------------------------------------
// Fused 2-layer LSTM on MFMA, bf16 hi/lo emulated-fp32 (3-pass), in-register
// DPP combine, role-split 16-wave block, dephased 2-phase schedule, x2
// unrolled t-loop (round-16 best state, unchanged this round).
// ---------------------------------------------------------------------------
__global__ __launch_bounds__(1024, 4)
void lstm_mfma(const float* __restrict__ x,
    const float* __restrict__ Wih0, const float* __restrict__ Whh0,
    const float* __restrict__ bih0, const float* __restrict__ bhh0,
    const float* __restrict__ Wih1, const float* __restrict__ Whh1,
    const float* __restrict__ bih1, const float* __restrict__ bhh1,
    const float* __restrict__ g1W, float* __restrict__ xw1out, int n)
{
  const int tid  = threadIdx.x;
  const int wv   = tid >> 6;     // wave 0..15
  const int role = wv >> 3;      // 0 = layer0 waves, 1 = layer1 waves
  const int w    = wv & 7;       // col-group within role
  const int l    = tid & 63;
  const int lr   = l & 15;       // A row (node) / B,D col-slot
  const int lg   = l >> 4;       // k-group 0..3
  const int nA   = blockIdx.x * NN;
  int avail = n - nA; if (avail > NN) avail = NN;

  __shared__ short Ax[2][2][16][40];   // [buf][hi/lo][node][f]
  __shared__ short H0[2][2][16][88];   // [buf][hi/lo][node][m]
  __shared__ short H1[2][16][88];      // [hi/lo][node][m] single time-buffer
  __shared__ float hf[16][64];         // final h1 (fp32) for xw1 fusion

  const int jm   = lr & 7;
  const bool lo8 = (lr < 15) && (lr < 8);
  const int col0 = (lr < 8) ? (8*w + jm) : (64  + 8*w + jm);       // i | f
  const int col1 = (lr < 8) ? (128 + 8*w + jm) : (192 + 8*w + jm); // g | o

  // ---- role-dependent weights -> split register fragments ----
  bf16x8 Wh[2][4], Wl[2][4];
  if (role == 0){
#pragma unroll
    for (int h = 0; h < 2; ++h){
      const int col = h ? col1 : col0;
      wsplit(Wih0 + col*FF + 8*lg,      Wh[h][0], Wl[h][0]);
      wsplit(Whh0 + col*HH + 8*lg,      Wh[h][1], Wl[h][1]);
      wsplit(Whh0 + col*HH + 32 + 8*lg, Wh[h][2], Wl[h][2]);
      Wh[h][3] = Wh[h][2]; Wl[h][3] = Wl[h][2];
    }
  } else {
#pragma unroll
    for (int h = 0; h < 2; ++h){
      const int col = h ? col1 : col0;
      wsplit(Wih1 + col*HH + 8*lg,      Wh[h][0], Wl[h][0]);
      wsplit(Wih1 + col*HH + 32 + 8*lg, Wh[h][1], Wl[h][1]);
      wsplit(Whh1 + col*HH + 8*lg,      Wh[h][2], Wl[h][2]);
      wsplit(Whh1 + col*HH + 32 + 8*lg, Wh[h][3], Wl[h][3]);
    }
  }
#pragma unroll
  for (int h = 0; h < 2; ++h)
#pragma unroll
    for (int k = 0; k < 4; ++k){ PIN(Wh[h][k]); PIN(Wl[h][k]); }

  // ---- per-lane pre-scaled gate biases for this role's layer, col m ----
  const int m = 8*w + jm;
  const float* bi = role ? bih1 : bih0;
  const float* bh = role ? bhh1 : bhh0;
  const float nb_i = -L2E      * (bi[m      ] + bh[m      ]);
  const float nb_f = -L2E      * (bi[m +  64] + bh[m +  64]);
  const float b2_g =  2.0f*L2E * (bi[m + 128] + bh[m + 128]);
  const float nb_o = -L2E      * (bi[m + 192] + bh[m + 192]);

  // ---- zero h planes; stage x(0) ----
  const int xnd = tid >> 5, xf = tid & 31;    // x staging role (tid<512)
  {
    short* p0 = &H0[0][0][0][0];
    for (int i = tid; i < 2*2*16*88; i += 1024) p0[i] = 0;
    short* p1 = &H1[0][0][0];
    for (int i = tid; i < 2*16*88; i += 1024) p1[i] = 0;
    if (tid < 512){
      float v = (xnd < avail) ? x[((size_t)(nA+xnd)*TT + 0)*FF + xf] : 0.0f;
      unsigned short hh, hl; split2(v, hh, hl);
      Ax[0][0][xnd][xf] = (short)hh;
      Ax[0][1][xnd][xf] = (short)hl;
    }
  }
  // hoisted per-thread x pointer: points at x(t=1); advanced FF per timestep
  const float* xp = x + ((size_t)(nA + xnd)*TT + 1)*FF + xf;
  const bool xok = (role == 0) && (xnd < avail);

  const int na = 4*lg + (lo8 ? 0 : 2);
  const int nb = na + 1;
  float ca = 0.0f, cb = 0.0f;
  f32x4 D0 = {0.f,0.f,0.f,0.f}, D1 = {0.f,0.f,0.f,0.f};
  const f32x4 Z = {0.f, 0.f, 0.f, 0.f};
  __syncthreads();

  for (int tt = 0; tt < TT; tt += 2){
#pragma unroll
    for (int p = 0; p < 2; ++p){
      const int t   = tt + p;
      const int rd0 = p ^ 1;     // compile-time buffer indices
      const int wr0 = p;
      f32x4 A0, A1;
      float xv = 0.0f;

      // ================== PHASE 1: L0 MFMA || L1 combine ==================
      if (role == 0){
        const int tp = t + 1;
        if (tp < TT && xok) xv = *xp;

        bf16x8 axh  = *(const bf16x8*)&Ax[p][0][lr][8*lg];
        bf16x8 axl  = *(const bf16x8*)&Ax[p][1][lr][8*lg];
        bf16x8 h0ah = *(const bf16x8*)&H0[rd0][0][lr][8*lg];
        bf16x8 h0al = *(const bf16x8*)&H0[rd0][1][lr][8*lg];
        bf16x8 h0bh = *(const bf16x8*)&H0[rd0][0][lr][32+8*lg];
        bf16x8 h0bl = *(const bf16x8*)&H0[rd0][1][lr][32+8*lg];

        __builtin_amdgcn_s_setprio(1);
        A0 = __builtin_amdgcn_mfma_f32_16x16x32_bf16(axl, Wh[0][0], Z, 0, 0, 0);
        A1 = __builtin_amdgcn_mfma_f32_16x16x32_bf16(axl, Wh[1][0], Z, 0, 0, 0);
        MFMA(A0, axh,  Wl[0][0]); MFMA(A0, axh,  Wh[0][0]);
        MFMA(A1, axh,  Wl[1][0]); MFMA(A1, axh,  Wh[1][0]);
        MFMA(A0, h0al, Wh[0][1]); MFMA(A0, h0ah, Wl[0][1]); MFMA(A0, h0ah, Wh[0][1]);
        MFMA(A1, h0al, Wh[1][1]); MFMA(A1, h0ah, Wl[1][1]); MFMA(A1, h0ah, Wh[1][1]);
        MFMA(A0, h0bl, Wh[0][2]); MFMA(A0, h0bh, Wl[0][2]); MFMA(A0, h0bh, Wh[0][2]);
        MFMA(A1, h0bl, Wh[1][2]); MFMA(A1, h0bh, Wl[1][2]); MFMA(A1, h0bh, Wh[1][2]);
        __builtin_amdgcn_s_setprio(0);
      }
      else if (t >= 2){
        // combine C1(t-2) from D0,D1 -> h1(t-2)
        f32x4 s0, s1;
        s0[0]=xor8(D0[0]); s0[1]=xor8(D0[1]); s0[2]=xor8(D0[2]); s0[3]=xor8(D0[3]);
        s1[0]=xor8(D1[0]); s1[1]=xor8(D1[1]); s1[2]=xor8(D1[2]); s1[3]=xor8(D1[3]);
        float gi_a = lo8 ? D0[0] : s0[2],  gi_b = lo8 ? D0[1] : s0[3];
        float gf_a = lo8 ? s0[0] : D0[2],  gf_b = lo8 ? s0[1] : D0[3];
        float gg_a = lo8 ? D1[0] : s1[2],  gg_b = lo8 ? D1[1] : s1[3];
        float go_a = lo8 ? s1[0] : D1[2],  go_b = lo8 ? s1[1] : D1[3];
        ca = sigm_nb(gf_a, nb_f)*ca + sigm_nb(gi_a, nb_i)*tanh_b(gg_a, b2_g);
        float ha = sigm_nb(go_a, nb_o)*tanh0(ca);
        cb = sigm_nb(gf_b, nb_f)*cb + sigm_nb(gi_b, nb_i)*tanh_b(gg_b, b2_g);
        float hb = sigm_nb(go_b, nb_o)*tanh0(cb);
        unsigned hi2, lo2; split_pk(ha, hb, hi2, lo2);
        H1[0][na][m] = (short)(hi2 & 0xFFFF);
        H1[0][nb][m] = (short)(hi2 >> 16);
        H1[1][na][m] = (short)(lo2 & 0xFFFF);
        H1[1][nb][m] = (short)(lo2 >> 16);
      }
      __syncthreads();

      // ================== PHASE 2: L0 combine || L1 MFMA ==================
      if (role == 0){
        f32x4 s0, s1;
        s0[0]=xor8(A0[0]); s0[1]=xor8(A0[1]); s0[2]=xor8(A0[2]); s0[3]=xor8(A0[3]);
        s1[0]=xor8(A1[0]); s1[1]=xor8(A1[1]); s1[2]=xor8(A1[2]); s1[3]=xor8(A1[3]);
        float gi_a = lo8 ? A0[0] : s0[2],  gi_b = lo8 ? A0[1] : s0[3];
        float gf_a = lo8 ? s0[0] : A0[2],  gf_b = lo8 ? s0[1] : A0[3];
        float gg_a = lo8 ? A1[0] : s1[2],  gg_b = lo8 ? A1[1] : s1[3];
        float go_a = lo8 ? s1[0] : A1[2],  go_b = lo8 ? s1[1] : A1[3];
        ca = sigm_nb(gf_a, nb_f)*ca + sigm_nb(gi_a, nb_i)*tanh_b(gg_a, b2_g);
        float ha = sigm_nb(go_a, nb_o)*tanh0(ca);
        cb = sigm_nb(gf_b, nb_f)*cb + sigm_nb(gi_b, nb_i)*tanh_b(gg_b, b2_g);
        float hb = sigm_nb(go_b, nb_o)*tanh0(cb);
        unsigned hi2, lo2; split_pk(ha, hb, hi2, lo2);
        H0[wr0][0][na][m] = (short)(hi2 & 0xFFFF);
        H0[wr0][0][nb][m] = (short)(hi2 >> 16);
        H0[wr0][1][na][m] = (short)(lo2 & 0xFFFF);
        H0[wr0][1][nb][m] = (short)(lo2 >> 16);
        // stage x(t+1) into buffer p^1 (pointer bump addressing)
        const int tp = t + 1;
        if (tp < TT && tid < 512){
          unsigned short hh, hl; split2(xv, hh, hl);
          Ax[p^1][0][xnd][xf] = (short)hh;
          Ax[p^1][1][xnd][xf] = (short)hl;
        }
      }
      else if (t >= 1){
        // MFMA G1(t-1): reads h0(t-1) [buf rd0] and h1(t-2)
        bf16x8 h0ah = *(const bf16x8*)&H0[rd0][0][lr][8*lg];
        bf16x8 h0al = *(const bf16x8*)&H0[rd0][1][lr][8*lg];
        bf16x8 h0bh = *(const bf16x8*)&H0[rd0][0][lr][32+8*lg];
        bf16x8 h0bl = *(const bf16x8*)&H0[rd0][1][lr][32+8*lg];

        __builtin_amdgcn_s_setprio(1);
        D0 = __builtin_amdgcn_mfma_f32_16x16x32_bf16(h0al, Wh[0][0], Z, 0, 0, 0);
        D1 = __builtin_amdgcn_mfma_f32_16x16x32_bf16(h0al, Wh[1][0], Z, 0, 0, 0);
        MFMA(D0, h0ah, Wl[0][0]); MFMA(D0, h0ah, Wh[0][0]);
        MFMA(D1, h0ah, Wl[1][0]); MFMA(D1, h0ah, Wh[1][0]);
        MFMA(D0, h0bl, Wh[0][1]); MFMA(D0, h0bh, Wl[0][1]); MFMA(D0, h0bh, Wh[0][1]);
        MFMA(D1, h0bl, Wh[1][1]); MFMA(D1, h0bh, Wl[1][1]); MFMA(D1, h0bh, Wh[1][1]);
        bf16x8 h1ah = *(const bf16x8*)&H1[0][lr][8*lg];
        bf16x8 h1al = *(const bf16x8*)&H1[1][lr][8*lg];
        bf16x8 h1bh = *(const bf16x8*)&H1[0][lr][32+8*lg];
        bf16x8 h1bl = *(const bf16x8*)&H1[1][lr][32+8*lg];
        MFMA(D0, h1al, Wh[0][2]); MFMA(D0, h1ah, Wl[0][2]); MFMA(D0, h1ah, Wh[0][2]);
        MFMA(D1, h1al, Wh[1][2]); MFMA(D1, h1ah, Wl[1][2]); MFMA(D1, h1ah, Wh[1][2]);
        MFMA(D0, h1bl, Wh[0][3]); MFMA(D0, h1bh, Wl[0][3]); MFMA(D0, h1bh, Wh[0][3]);
        MFMA(D1, h1bl, Wh[1][3]); MFMA(D1, h1bh, Wl[1][3]); MFMA(D1, h1bh, Wh[1][3]);
        __builtin_amdgcn_s_setprio(0);
      }
      __syncthreads();
      xp += FF;   // advance to next timestep's x
    }
  }

  // ================== epilogue ==================
  if (role == 1){
    f32x4 s0, s1;
    s0[0]=xor8(D0[0]); s0[1]=xor8(D0[1]); s0[2]=xor8(D0[2]); s0[3]=xor8(D0[3]);
    s1[0]=xor8(D1[0]); s1[1]=xor8(D1[1]); s1[2]=xor8(D1[2]); s1[3]=xor8(D1[3]);
    float gi_a = lo8 ? D0[0] : s0[2],  gi_b = lo8 ? D0[1] : s0[3];
    float gf_a = lo8 ? s0[0] : D0[2],  gf_b = lo8 ? s0[1] : D0[3];
    float gg_a = lo8 ? D1[0] : s1[2],  gg_b = lo8 ? D1[1] : s1[3];
    float go_a = lo8 ? s1[0] : D1[2],  go_b = lo8 ? s1[1] : D1[3];
    ca = sigm_nb(gf_a, nb_f)*ca + sigm_nb(gi_a, nb_i)*tanh_b(gg_a, b2_g);
    float ha = sigm_nb(go_a, nb_o)*tanh0(ca);
    cb = sigm_nb(gf_b, nb_f)*cb + sigm_nb(gi_b, nb_i)*tanh_b(gg_b, b2_g);
    float hb = sigm_nb(go_b, nb_o)*tanh0(cb);
    unsigned hi2, lo2; split_pk(ha, hb, hi2, lo2);
    H1[0][na][m] = (short)(hi2 & 0xFFFF);
    H1[0][nb][m] = (short)(hi2 >> 16);
    H1[1][na][m] = (short)(lo2 & 0xFFFF);
    H1[1][nb][m] = (short)(lo2 >> 16);
  }
  __syncthreads();
  if (role == 1){
    const int rd0 = (TT-1) & 1;      // h0(TT-1)
    bf16x8 h0ah = *(const bf16x8*)&H0[rd0][0][lr][8*lg];
    bf16x8 h0al = *(const bf16x8*)&H0[rd0][1][lr][8*lg];
    bf16x8 h0bh = *(const bf16x8*)&H0[rd0][0][lr][32+8*lg];
    bf16x8 h0bl = *(const bf16x8*)&H0[rd0][1][lr][32+8*lg];
    bf16x8 h1ah = *(const bf16x8*)&H1[0][lr][8*lg];
    bf16x8 h1al = *(const bf16x8*)&H1[1][lr][8*lg];
    bf16x8 h1bh = *(const bf16x8*)&H1[0][lr][32+8*lg];
    bf16x8 h1bl = *(const bf16x8*)&H1[1][lr][32+8*lg];
    f32x4 E0 = __builtin_amdgcn_mfma_f32_16x16x32_bf16(h0al, Wh[0][0], Z, 0, 0, 0);
    f32x4 E1 = __builtin_amdgcn_mfma_f32_16x16x32_bf16(h0al, Wh[1][0], Z, 0, 0, 0);
    MFMA(E0, h0ah, Wl[0][0]); MFMA(E0, h0ah, Wh[0][0]);
    MFMA(E1, h0ah, Wl[1][0]); MFMA(E1, h0ah, Wh[1][0]);
    MFMA(E0, h0bl, Wh[0][1]); MFMA(E0, h0bh, Wl[0][1]); MFMA(E0, h0bh, Wh[0][1]);
    MFMA(E1, h0bl, Wh[1][1]); MFMA(E1, h0bh, Wl[1][1]); MFMA(E1, h0bh, Wh[1][1]);
    MFMA(E0, h1al, Wh[0][2]); MFMA(E0, h1ah, Wl[0][2]); MFMA(E0, h1ah, Wh[0][2]);
    MFMA(E1, h1al, Wh[1][2]); MFMA(E1, h1ah, Wl[1][2]); MFMA(E1, h1ah, Wh[1][2]);
    MFMA(E0, h1bl, Wh[0][3]); MFMA(E0, h1bh, Wl[0][3]); MFMA(E0, h1bh, Wh[0][3]);
    MFMA(E1, h1bl, Wh[1][3]); MFMA(E1, h1bh, Wl[1][3]); MFMA(E1, h1bh, Wh[1][3]);

    f32x4 s0, s1;
    s0[0]=xor8(E0[0]); s0[1]=xor8(E0[1]); s0[2]=xor8(E0[2]); s0[3]=xor8(E0[3]);
    s1[0]=xor8(E1[0]); s1[1]=xor8(E1[1]); s1[2]=xor8(E1[2]); s1[3]=xor8(E1[3]);
    float gi_a = lo8 ? E0[0] : s0[2],  gi_b = lo8 ? E0[1] : s0[3];
    float gf_a = lo8 ? s0[0] : E0[2],  gf_b = lo8 ? s0[1] : E0[3];
    float gg_a = lo8 ? E1[0] : s1[2],  gg_b = lo8 ? E1[1] : s1[3];
    float go_a = lo8 ? s1[0] : E1[2],  go_b = lo8 ? s1[1] : E1[3];
    ca = sigm_nb(gf_a, nb_f)*ca + sigm_nb(gi_a, nb_i)*tanh_b(gg_a, b2_g);
    float ha = sigm_nb(go_a, nb_o)*tanh0(ca);
    cb = sigm_nb(gf_b, nb_f)*cb + sigm_nb(gi_b, nb_i)*tanh_b(gg_b, b2_g);
    float hb = sigm_nb(go_b, nb_o)*tanh0(cb);
    hf[na][m] = ha;
    hf[nb][m] = hb;
  }
  __syncthreads();

  // ---- fused xw1 = h1_final @ g1W (one output per thread; wave==node) ----
  {
    const int node = tid >> 6;
    const int col  = tid & 63;
    if (node < avail){
      float acc = 0.0f;
#pragma unroll
      for (int k = 0; k < HH; ++k)
        acc = fmaf(hf[node][k], g1W[k*GG1 + col], acc);
      xw1out[(size_t)(nA + node)*GG1 + col] = acc;
    }
  }
}

// ---------------------------------------------------------------------------
// GCN support kernels
// ---------------------------------------------------------------------------
__global__ void k_count(const int* __restrict__ dst, int E, int* __restrict__ cnt)
{
  int e = (blockIdx.x * blockDim.x + threadIdx.x) * 4;
  if (e + 3 < E) {
    int4 d = *(const int4*)&dst[e];
    atomicAdd(&cnt[d.x], 1); atomicAdd(&cnt[d.y], 1);
    atomicAdd(&cnt[d.z], 1); atomicAdd(&cnt[d.w], 1);
  } else {
    for (int k = e; k < E; ++k) atomicAdd(&cnt[dst[k]], 1);
  }
}

__global__ void k_scan_build(const int* __restrict__ cnt, int n,
                             int* __restrict__ offs, int* __restrict__ cursor,
                             float* __restrict__ dinv)
{
  __shared__ int part[1024];
  const int tid = threadIdx.x;
  const int per = (n + 1023) >> 10;
  const int base = tid * per;
  int s = 0;
  for (int i = 0; i < per; ++i) { int idx = base + i; if (idx < n) s += cnt[idx]; }
  part[tid] = s;
  __syncthreads();
  for (int off = 1; off < 1024; off <<= 1) {
    int v = 0;
    if (tid >= off) v = part[tid - off];
    __syncthreads();
    part[tid] += v;
    __syncthreads();
  }
  int run = part[tid] - s;
  for (int i = 0; i < per; ++i) {
    int idx = base + i;
    if (idx < n) {
      offs[idx] = run; cursor[idx] = run;
      int c = cnt[idx];
      dinv[idx] = 1.0f / sqrtf((float)(c + 1));
      run += c;
    }
  }
}

__global__ void k_fill(const int* __restrict__ src, const int* __restrict__ dst,
                       int E, int* __restrict__ cursor, int* __restrict__ csr)
{
  int e = (blockIdx.x * blockDim.x + threadIdx.x) * 4;
  if (e + 3 < E) {
    int4 d = *(const int4*)&dst[e];
    int4 s = *(const int4*)&src[e];
    csr[atomicAdd(&cursor[d.x], 1)] = s.x;
    csr[atomicAdd(&cursor[d.y], 1)] = s.y;
    csr[atomicAdd(&cursor[d.z], 1)] = s.z;
    csr[atomicAdd(&cursor[d.w], 1)] = s.w;
  } else {
    for (int k = e; k < E; ++k) {
      int pos = atomicAdd(&cursor[dst[k]], 1);
      csr[pos] = src[k];
    }
  }
}

// CSR aggregate for layer1 (FD=64) + bias/relu, FUSED with xw2 = g1 @ W2.
__global__ void k_agg_x2(const float* __restrict__ xw, const int* __restrict__ offs,
                         const int* __restrict__ cnt, const int* __restrict__ csr,
                         const float* __restrict__ dinv, const float* __restrict__ b,
                         const float* __restrict__ W2,
                         float* __restrict__ xw2out, int n)
{
  __shared__ float sg[4][GG1];
  const int nd   = threadIdx.x >> 6;
  const int lane = threadIdx.x & 63;
  const int node = blockIdx.x * 4 + nd;
  if (node < n) {
    const float di = dinv[node];
    float acc = xw[(size_t)node*GG1 + lane] * di * di;
    const int s0 = offs[node], e0 = s0 + cnt[node];
    for (int p = s0; p < e0; ++p) {
      int s = csr[p];
      acc = fmaf(xw[(size_t)s*GG1 + lane], dinv[s] * di, acc);
    }
    sg[nd][lane] = fmaxf(acc + b[lane], 0.0f);
  }
  __syncthreads();
  if (node < n && lane < GG2) {
    float a2 = 0.0f;
#pragma unroll
    for (int k = 0; k < GG1; ++k) a2 = fmaf(sg[nd][k], W2[k*GG2 + lane], a2);
    xw2out[(size_t)node*GG2 + lane] = a2;
  }
}

// CSR aggregate layer2 (FD=32) + bias/relu, FUSED with fc dot: writes
// fcval[node] = relu(agg + b) . fcW + fcb  (shfl tree over the 32 lanes).
__global__ void k_agg_fc(const float* __restrict__ xw2, const int* __restrict__ offs,
                         const int* __restrict__ cnt, const int* __restrict__ csr,
                         const float* __restrict__ dinv, const float* __restrict__ b,
                         const float* __restrict__ fcW, const float* __restrict__ fcb,
                         float* __restrict__ fcval, int n)
{
  int gidx = blockIdx.x * blockDim.x + threadIdx.x;
  int node = gidx >> 5, lane = gidx & 31;
  float acc = 0.0f;
  const bool ok = (node < n);
  if (ok) {
    const float di = dinv[node];
    acc = xw2[(size_t)node*GG2 + lane] * di * di;
    const int s0 = offs[node], e0 = s0 + cnt[node];
    for (int p = s0; p < e0; ++p) {
      int s = csr[p];
      acc = fmaf(xw2[(size_t)s*GG2 + lane], dinv[s] * di, acc);
    }
    acc = fmaxf(acc + b[lane], 0.0f) * fcW[lane];
  }
  // reduce across the 32 lanes of this node (masks <=16 stay in-group)
  acc += __shfl_xor(acc, 1);
  acc += __shfl_xor(acc, 2);
  acc += __shfl_xor(acc, 4);
  acc += __shfl_xor(acc, 8);
  acc += __shfl_xor(acc, 16);
  if (ok && lane == 0) fcval[node] = acc + fcb[0];
}

__global__ void k_gather(const float* __restrict__ fcval, const int* __restrict__ sid,
                         float* __restrict__ out, int n)
{
  int i = blockIdx.x * blockDim.x + threadIdx.x;
  if (i < n) out[i] = fcval[sid[i]];
}

// ---------------------------------------------------------------------------
extern "C" void kernel_launch(void* const* d_in, const int* in_sizes, int n_in,
                              void* d_out, int out_size, void* d_ws, size_t ws_size,
                              hipStream_t stream)
{
  const float* x    = (const float*)d_in[0];
  const int*   sid  = (const int*)  d_in[1];
  const int*   eidx = (const int*)  d_in[2];
  const float* Wih0 = (const float*)d_in[3];
  const float* Whh0 = (const float*)d_in[4];
  const float* bih0 = (const float*)d_in[5];
  const float* bhh0 = (const float*)d_in[6];
  const float* Wih1 = (const float*)d_in[7];
  const float* Whh1 = (const float*)d_in[8];
  const float* bih1 = (const float*)d_in[9];
  const float* bhh1 = (const float*)d_in[10];
  const float* g1W  = (const float*)d_in[11];
  const float* g1b  = (const float*)d_in[12];
  const float* g2W  = (const float*)d_in[13];
  const float* g2b  = (const float*)d_in[14];
  const float* fcW  = (const float*)d_in[15];
  const float* fcb  = (const float*)d_in[16];

  const int n = in_sizes[1];
  const int E = in_sizes[2] / 2;
  float* out = (float*)d_out;

  char* w = (char*)d_ws;
  auto carve = [&](size_t bytes) -> void* {
    void* p = (void*)w; w += (bytes + 255) & ~(size_t)255; return p;
  };
  int*   cnt    = (int*)  carve((size_t)n * 4);
  int*   offs   = (int*)  carve((size_t)n * 4);
  int*   cursor = (int*)  carve((size_t)n * 4);
  float* dinv   = (float*)carve((size_t)n * 4);
  int*   csr    = (int*)  carve((size_t)E * 4);
  float* xw1    = (float*)carve((size_t)n * GG1 * 4);
  float* xw2    = (float*)carve((size_t)n * GG2 * 4);
  float* fcval  = (float*)carve((size_t)n * 4);

  const int* src = eidx;
  const int* dst = eidx + E;

  lstm_mfma<<<(n + NN - 1) / NN, 1024, 0, stream>>>(x, Wih0, Whh0, bih0, bhh0,
                                                    Wih1, Whh1, bih1, bhh1,
                                                    g1W, xw1, n);

  hipMemsetAsync(cnt, 0, (size_t)n * 4, stream);
  k_count<<<(E/4 + 255) / 256, 256, 0, stream>>>(dst, E, cnt);
  k_scan_build<<<1, 1024, 0, stream>>>(cnt, n, offs, cursor, dinv);
  k_fill<<<(E/4 + 255) / 256, 256, 0, stream>>>(src, dst, E, cursor, csr);

  k_agg_x2<<<(n + 3) / 4, 256, 0, stream>>>(xw1, offs, cnt, csr, dinv, g1b, g2W, xw2, n);

  k_agg_fc<<<((size_t)n * GG2 + 255) / 256, 256, 0, stream>>>(xw2, offs, cnt, csr, dinv,
                                                              g2b, fcW, fcb, fcval, n);

  k_gather<<<(n + 255) / 256, 256, 0, stream>>>(fcval, sid, out, n);
}